// Round 6
// baseline (4230.932 us; speedup 1.0000x reference)
//
#include <hip/hip_runtime.h>

#define STEPS 6

typedef __attribute__((ext_vector_type(8))) short short8;
typedef __attribute__((ext_vector_type(4))) float f32x4;

__device__ __forceinline__ float bf2f(unsigned int u16) {
    union { unsigned int u; float f; } v; v.u = u16 << 16; return v.f;
}
__device__ __forceinline__ unsigned int f2bf(float x) {
    union { float f; unsigned int u; } v; v.f = x;
    unsigned int r = v.u + 0x7fffu + ((v.u >> 16) & 1u);
    return r >> 16;
}
__device__ __forceinline__ void decomp8(const float* __restrict__ ap, short8& hi, short8& lo) {
#pragma unroll
    for (int j = 0; j < 8; ++j) {
        float v = ap[j];
        unsigned int h = f2bf(v);
        hi[j] = (short)h;
        lo[j] = (short)f2bf(v - bf2f(h));
    }
}

// ---------------- CSR build ----------------
__global__ __launch_bounds__(256) void hist_k(const int* __restrict__ dst, int* __restrict__ deg, int E) {
    int e = blockIdx.x * 256 + threadIdx.x;
    if (e < E) atomicAdd(&deg[dst[e]], 1);
}

__global__ __launch_bounds__(256) void scan1_k(const int* __restrict__ in, int* __restrict__ ex,
                                               int* __restrict__ bs, int N) {
    __shared__ int sd[256];
    int t = threadIdx.x;
    int base = blockIdx.x * 1024 + t * 4;
    int v[4]; int s = 0;
#pragma unroll
    for (int i = 0; i < 4; ++i) { int idx = base + i; v[i] = idx < N ? in[idx] : 0; s += v[i]; }
    sd[t] = s; __syncthreads();
    for (int o = 1; o < 256; o <<= 1) {
        int x = (t >= o) ? sd[t - o] : 0;
        __syncthreads();
        sd[t] += x;
        __syncthreads();
    }
    int run = sd[t] - s;
#pragma unroll
    for (int i = 0; i < 4; ++i) { int idx = base + i; if (idx < N) ex[idx] = run; run += v[i]; }
    if (t == 255) bs[blockIdx.x] = sd[255];
}

__global__ __launch_bounds__(1024) void scan2_k(const int* __restrict__ bs, int* __restrict__ be, int nb) {
    __shared__ int sd[1024];
    int t = threadIdx.x;
    int v = (t < nb) ? bs[t] : 0;
    sd[t] = v; __syncthreads();
    for (int o = 1; o < 1024; o <<= 1) {
        int x = (t >= o) ? sd[t - o] : 0;
        __syncthreads();
        sd[t] += x;
        __syncthreads();
    }
    if (t < nb) be[t] = sd[t] - v;
}

__global__ __launch_bounds__(256) void scan3_k(const int* __restrict__ ex, const int* __restrict__ be,
                                               int* __restrict__ offs, int N, int E) {
    int i = blockIdx.x * 256 + threadIdx.x;
    if (i < N) offs[i] = ex[i] + be[i >> 10];
    if (i == N) offs[N] = E;
}

__global__ __launch_bounds__(256) void scatter_k(const int* __restrict__ src, const int* __restrict__ dst,
                                                 const int* __restrict__ offs,
                                                 int* __restrict__ cursor, int* __restrict__ src_sorted,
                                                 int* __restrict__ eid_sorted, int E) {
    int e = blockIdx.x * 256 + threadIdx.x;
    if (e >= E) return;
    int d = dst[e];
    int pos = offs[d] + atomicAdd(&cursor[d], 1);
    src_sorted[pos] = src[e];
    eid_sorted[pos] = e;
}

// ---------------- weight packing: hi+lo bf16 planes, B-fragment order ----------------
// frag addr: ((ct*KS + ks)*64 + lane)*8 + j ; k = ks*32 + (lane>>4)*8 + j, col = ct*16 + (lane&15)
// per-step (stride 294912 elems): hi plane at +0, lo plane at +147456
// mat offsets (elems): W1:0 (32768), W2:32768 (16384), Wz:49152, Wr:81920, Wh:114688
__global__ __launch_bounds__(256) void pack_k(const float* __restrict__ W_m1, const float* __restrict__ W_m2,
                                              const float* __restrict__ W_z, const float* __restrict__ W_r,
                                              const float* __restrict__ W_h, unsigned short* __restrict__ packed) {
    const int s = blockIdx.y, mat = blockIdx.z;
    const int t = blockIdx.x * 256 + threadIdx.x;
    const int lane = t & 63;
    int KS, width; size_t moff;
    if (mat == 0)      { KS = 4; width = 256; moff = 0; }
    else if (mat == 1) { KS = 4; width = 128; moff = 32768; }
    else if (mat == 2) { KS = 8; width = 128; moff = 49152; }
    else if (mat == 3) { KS = 8; width = 128; moff = 81920; }
    else               { KS = 8; width = 128; moff = 114688; }
    const int total = (width >> 4) * KS * 64;
    if (t >= total) return;
    const int ks = (t >> 6) % KS;
    const int ct = (t >> 6) / KS;
    const int col = ct * 16 + (lane & 15);
    const int kb = ks * 32 + (lane >> 4) * 8;
    unsigned short* dh = packed + (size_t)s * 294912 + moff;
    unsigned short* dl = dh + 147456;
#pragma unroll
    for (int j = 0; j < 8; ++j) {
        const int k = kb + j;
        float v;
        if (mat == 0) {
            const float* W = W_m1 + (size_t)s * 260 * 128;
            v = (col < 128) ? W[k * 128 + col] : W[(128 + k) * 128 + (col - 128)];
        } else if (mat == 1) {
            v = W_m2[(size_t)s * 16384 + k * 128 + col];
        } else if (mat == 2) {
            v = W_z[(size_t)s * 32768 + k * 128 + col];
        } else if (mat == 3) {
            v = W_r[(size_t)s * 32768 + k * 128 + col];
        } else {
            v = W_h[(size_t)s * 32768 + k * 128 + col];
        }
        unsigned int hb = f2bf(v);
        dh[(size_t)t * 8 + j] = (unsigned short)hb;
        dl[(size_t)t * 8 + j] = (unsigned short)f2bf(v - bf2f(hb));
    }
}

// ---------------- input projection -> f32 h ----------------
__global__ __launch_bounds__(256) void proj_k(const float* __restrict__ nf, const float* __restrict__ Win,
                                              const float* __restrict__ bin,
                                              float* __restrict__ hf, int N) {
    const int lane = threadIdx.x & 63, wave = threadIdx.x >> 6;
    const int i = blockIdx.x * 4 + wave;
    if (i >= N) return;
    const int c0 = lane * 2;
    float a0 = bin[c0], a1 = bin[c0 + 1];
#pragma unroll
    for (int q = 0; q < 8; ++q) {
        float x = nf[(size_t)i * 8 + q];
        a0 += x * Win[q * 128 + c0];
        a1 += x * Win[q * 128 + c0 + 1];
    }
    hf[(size_t)i * 128 + c0] = a0;
    hf[(size_t)i * 128 + c0 + 1] = a1;
}

// ---------------- f32-accurate MFMA GEMM (3-MFMA hi/lo scheme) ----------------
// MODE 0: X = h@[W1s|W1d] : A=hf lda=128, out=X ldo=256 (cols cgrp*128..)
// MODE 1: agg = T@W2 + deg*b : A=X+128 lda=256, out=X ldo=256 (cols 0:128)
template <int MODE>
__global__ __launch_bounds__(256) void gemm_k(const float* __restrict__ A, int lda,
                                              const unsigned short* __restrict__ pkh,
                                              const unsigned short* __restrict__ pkl,
                                              const float* __restrict__ bias,
                                              const int* __restrict__ deg,
                                              float* __restrict__ out, int ldo,
                                              int Nrows, int K) {
    const int lane = threadIdx.x & 63;
    const int wave = threadIdx.x >> 6;
    const int l15 = lane & 15, l16 = lane >> 4;
    const int mbase = blockIdx.x * 128 + wave * 32;
    const int cgrp = blockIdx.y;
    const int KS = K >> 5;
    f32x4 acc[2][8];
#pragma unroll
    for (int rt = 0; rt < 2; ++rt)
#pragma unroll
        for (int ct = 0; ct < 8; ++ct) acc[rt][ct] = (f32x4){0.f, 0.f, 0.f, 0.f};

    for (int ks = 0; ks < KS; ++ks) {
        const int k = ks * 32 + l16 * 8;
        short8 ahi[2], alo[2];
#pragma unroll
        for (int rt = 0; rt < 2; ++rt) {
            int row = mbase + rt * 16 + l15;
            row = row < Nrows ? row : 0;
            decomp8(A + (size_t)row * lda + k, ahi[rt], alo[rt]);
        }
#pragma unroll
        for (int ct = 0; ct < 8; ++ct) {
            const size_t fb = ((size_t)((cgrp * 8 + ct) * KS + ks) * 64 + lane) * 8;
            const short8 wh = *reinterpret_cast<const short8*>(pkh + fb);
            const short8 wl = *reinterpret_cast<const short8*>(pkl + fb);
#pragma unroll
            for (int rt = 0; rt < 2; ++rt) {
                acc[rt][ct] = __builtin_amdgcn_mfma_f32_16x16x32_bf16(ahi[rt], wh, acc[rt][ct], 0, 0, 0);
                acc[rt][ct] = __builtin_amdgcn_mfma_f32_16x16x32_bf16(alo[rt], wh, acc[rt][ct], 0, 0, 0);
                acc[rt][ct] = __builtin_amdgcn_mfma_f32_16x16x32_bf16(ahi[rt], wl, acc[rt][ct], 0, 0, 0);
            }
        }
    }
#pragma unroll
    for (int rt = 0; rt < 2; ++rt) {
#pragma unroll
        for (int ct = 0; ct < 8; ++ct) {
            const int col = cgrp * 128 + ct * 16 + l15;
#pragma unroll
            for (int r = 0; r < 4; ++r) {
                const int row = mbase + rt * 16 + l16 * 4 + r;
                if (row >= Nrows) continue;
                float v = acc[rt][ct][r];
                if (MODE == 1) v += bias[col] * (float)deg[row];
                out[(size_t)row * ldo + col] = v;
            }
        }
    }
}

// ---------------- fused z,r,rh,hn,blend,LN ----------------
// z = sig([h|agg]@Wz+bz); r = sig([h|agg]@Wr+br); rh = r*h (redistributed via LDS hi/lo);
// hn = tanh([rh|agg]@Wh+bh); h = LN((1-z)h + z*hn)  -- all f32, 3-MFMA scheme.
__global__ __launch_bounds__(256) void zrh_k(float* __restrict__ hf,
                                             const float* __restrict__ Xa,  // agg at [row*256 + 0..127]
                                             const unsigned short* __restrict__ pzh, const unsigned short* __restrict__ pzl,
                                             const unsigned short* __restrict__ prh, const unsigned short* __restrict__ prl,
                                             const unsigned short* __restrict__ phh, const unsigned short* __restrict__ phl,
                                             const float* __restrict__ bz, const float* __restrict__ br,
                                             const float* __restrict__ bh,
                                             const float* __restrict__ lns, const float* __restrict__ lnb,
                                             int N) {
    __shared__ unsigned int lds[4][32][128];  // 64 KB: per-wave rh tile (hi|lo bf16 in u32)
    const int lane = threadIdx.x & 63;
    const int wave = threadIdx.x >> 6;
    const int l15 = lane & 15, l16 = lane >> 4;
    const int mbase = blockIdx.x * 128 + wave * 32;

    // ---- phase 1: z_pre, r_pre over K=256 ([h | agg]) ----
    f32x4 zac[2][8], rac[2][8];
#pragma unroll
    for (int rt = 0; rt < 2; ++rt)
#pragma unroll
        for (int ct = 0; ct < 8; ++ct) {
            zac[rt][ct] = (f32x4){0.f, 0.f, 0.f, 0.f};
            rac[rt][ct] = (f32x4){0.f, 0.f, 0.f, 0.f};
        }
    for (int ks = 0; ks < 8; ++ks) {
        const int k = ks * 32 + l16 * 8;
        short8 ahi[2], alo[2];
#pragma unroll
        for (int rt = 0; rt < 2; ++rt) {
            int row = mbase + rt * 16 + l15;
            row = row < N ? row : 0;
            const float* ap = (k < 128) ? (hf + (size_t)row * 128 + k)
                                        : (Xa + (size_t)row * 256 + (k - 128));
            decomp8(ap, ahi[rt], alo[rt]);
        }
#pragma unroll
        for (int ct = 0; ct < 8; ++ct) {
            const size_t fb = ((size_t)(ct * 8 + ks) * 64 + lane) * 8;
            const short8 wzh = *reinterpret_cast<const short8*>(pzh + fb);
            const short8 wzl = *reinterpret_cast<const short8*>(pzl + fb);
            const short8 wrh = *reinterpret_cast<const short8*>(prh + fb);
            const short8 wrl = *reinterpret_cast<const short8*>(prl + fb);
#pragma unroll
            for (int rt = 0; rt < 2; ++rt) {
                zac[rt][ct] = __builtin_amdgcn_mfma_f32_16x16x32_bf16(ahi[rt], wzh, zac[rt][ct], 0, 0, 0);
                zac[rt][ct] = __builtin_amdgcn_mfma_f32_16x16x32_bf16(alo[rt], wzh, zac[rt][ct], 0, 0, 0);
                zac[rt][ct] = __builtin_amdgcn_mfma_f32_16x16x32_bf16(ahi[rt], wzl, zac[rt][ct], 0, 0, 0);
                rac[rt][ct] = __builtin_amdgcn_mfma_f32_16x16x32_bf16(ahi[rt], wrh, rac[rt][ct], 0, 0, 0);
                rac[rt][ct] = __builtin_amdgcn_mfma_f32_16x16x32_bf16(alo[rt], wrh, rac[rt][ct], 0, 0, 0);
                rac[rt][ct] = __builtin_amdgcn_mfma_f32_16x16x32_bf16(ahi[rt], wrl, rac[rt][ct], 0, 0, 0);
            }
        }
    }

    // ---- phase 2: z = sigmoid; rh = sigmoid(r)*h -> LDS (hi|lo u32, XOR-swizzled) ----
#pragma unroll
    for (int rt = 0; rt < 2; ++rt)
#pragma unroll
        for (int ct = 0; ct < 8; ++ct) {
            const int col = ct * 16 + l15;
#pragma unroll
            for (int r = 0; r < 4; ++r) {
                const int rowl = rt * 16 + l16 * 4 + r;
                const int row = mbase + rowl;
                const size_t idx = (size_t)(row < N ? row : 0) * 128 + col;
                float zp = zac[rt][ct][r] + bz[col];
                zac[rt][ct][r] = 1.f / (1.f + expf(-zp));
                float rp = rac[rt][ct][r] + br[col];
                float rr = 1.f / (1.f + expf(-rp));
                float rh = rr * hf[idx];
                unsigned int hb = f2bf(rh);
                unsigned int lb = f2bf(rh - bf2f(hb));
                lds[wave][rowl][col ^ ((rowl & 7) << 4)] = hb | (lb << 16);
            }
        }
    __syncthreads();

    // ---- phase 3: hn_pre over K=256 ([rh | agg]) ----
    f32x4 hac[2][8];
#pragma unroll
    for (int rt = 0; rt < 2; ++rt)
#pragma unroll
        for (int ct = 0; ct < 8; ++ct) hac[rt][ct] = (f32x4){0.f, 0.f, 0.f, 0.f};
    for (int ks = 0; ks < 8; ++ks) {
        const int k = ks * 32 + l16 * 8;
        short8 ahi[2], alo[2];
#pragma unroll
        for (int rt = 0; rt < 2; ++rt) {
            const int lrow = rt * 16 + l15;
            if (k < 128) {
                const unsigned int* lp = &lds[wave][lrow][k ^ ((lrow & 7) << 4)];
#pragma unroll
                for (int j = 0; j < 8; ++j) {
                    unsigned int u = lp[j];
                    ahi[rt][j] = (short)(u & 0xffffu);
                    alo[rt][j] = (short)(u >> 16);
                }
            } else {
                int row = mbase + lrow;
                row = row < N ? row : 0;
                decomp8(Xa + (size_t)row * 256 + (k - 128), ahi[rt], alo[rt]);
            }
        }
#pragma unroll
        for (int ct = 0; ct < 8; ++ct) {
            const size_t fb = ((size_t)(ct * 8 + ks) * 64 + lane) * 8;
            const short8 wh = *reinterpret_cast<const short8*>(phh + fb);
            const short8 wl = *reinterpret_cast<const short8*>(phl + fb);
#pragma unroll
            for (int rt = 0; rt < 2; ++rt) {
                hac[rt][ct] = __builtin_amdgcn_mfma_f32_16x16x32_bf16(ahi[rt], wh, hac[rt][ct], 0, 0, 0);
                hac[rt][ct] = __builtin_amdgcn_mfma_f32_16x16x32_bf16(alo[rt], wh, hac[rt][ct], 0, 0, 0);
                hac[rt][ct] = __builtin_amdgcn_mfma_f32_16x16x32_bf16(ahi[rt], wl, hac[rt][ct], 0, 0, 0);
            }
        }
    }

    // ---- phase 4: blend + LayerNorm -> hf ----
#pragma unroll
    for (int rt = 0; rt < 2; ++rt)
#pragma unroll
        for (int ct = 0; ct < 8; ++ct) {
            const int col = ct * 16 + l15;
#pragma unroll
            for (int r = 0; r < 4; ++r) {
                const int row = mbase + rt * 16 + l16 * 4 + r;
                const size_t idx = (size_t)(row < N ? row : 0) * 128 + col;
                float hn = tanhf(hac[rt][ct][r] + bh[col]);
                float zz = zac[rt][ct][r];
                hac[rt][ct][r] = (1.f - zz) * hf[idx] + zz * hn;
            }
        }
#pragma unroll
    for (int rt = 0; rt < 2; ++rt)
#pragma unroll
        for (int r = 0; r < 4; ++r) {
            const int row = mbase + rt * 16 + l16 * 4 + r;
            float s = 0.f, ss = 0.f;
#pragma unroll
            for (int ct = 0; ct < 8; ++ct) {
                float y = hac[rt][ct][r];
                s += y; ss += y * y;
            }
#pragma unroll
            for (int m = 1; m < 16; m <<= 1) {
                s += __shfl_xor(s, m, 64);
                ss += __shfl_xor(ss, m, 64);
            }
            float mean = s * (1.f / 128.f);
            float var = ss * (1.f / 128.f) - mean * mean;
            float inv = rsqrtf(var + 1e-6f);
            if (row < N) {
#pragma unroll
                for (int ct = 0; ct < 8; ++ct) {
                    const int col = ct * 16 + l15;
                    hf[(size_t)row * 128 + col] = (hac[rt][ct][r] - mean) * inv * lns[col] + lnb[col];
                }
            }
        }
}

// ---------------- edge accumulate (f32): T[v] = sum relu(Xs[src]+Xd[v]+ef@Wef+b1), T -> X[:,128:256] ----
__global__ __launch_bounds__(256) void edge_k(float* __restrict__ X,
                                              const int* __restrict__ offs,
                                              const int* __restrict__ src_sorted,
                                              const int* __restrict__ eid_sorted,
                                              const float4* __restrict__ ef_all,
                                              const float* __restrict__ Wm1_s,
                                              const float* __restrict__ bm1_s,
                                              int N) {
    const int lane = threadIdx.x & 63, wave = threadIdx.x >> 6;
    const int v = blockIdx.x * 4 + wave;
    if (v >= N) return;
    const int c0 = lane * 2;
    const float base0 = X[(size_t)v * 256 + 128 + c0] + bm1_s[c0];
    const float base1 = X[(size_t)v * 256 + 129 + c0] + bm1_s[c0 + 1];
    const float w0x = Wm1_s[256 * 128 + c0], w0y = Wm1_s[256 * 128 + c0 + 1];
    const float w1x = Wm1_s[257 * 128 + c0], w1y = Wm1_s[257 * 128 + c0 + 1];
    const float w2x = Wm1_s[258 * 128 + c0], w2y = Wm1_s[258 * 128 + c0 + 1];
    const float w3x = Wm1_s[259 * 128 + c0], w3y = Wm1_s[259 * 128 + c0 + 1];
    float acc0 = 0.f, acc1 = 0.f;
    const int beg = offs[v], end = offs[v + 1];
    for (int i = beg; i < end; ++i) {
        int sn = src_sorted[i];
        int eid = eid_sorted[i];
        float4 ef = ef_all[eid];
        float2 xs = *reinterpret_cast<const float2*>(X + (size_t)sn * 256 + c0);
        float e0 = ef.x * w0x + ef.y * w1x + ef.z * w2x + ef.w * w3x;
        float e1 = ef.x * w0y + ef.y * w1y + ef.z * w2y + ef.w * w3y;
        acc0 += fmaxf(xs.x + base0 + e0, 0.f);
        acc1 += fmaxf(xs.y + base1 + e1, 0.f);
    }
    X[(size_t)v * 256 + 128 + c0] = acc0;   // T overwrites Xd (consumed above)
    X[(size_t)v * 256 + 129 + c0] = acc1;
}

// ---------------- heads (f32) ----------------
__global__ __launch_bounds__(256) void head_k(const float* __restrict__ h,
                                              const float* __restrict__ Wc1, const float* __restrict__ bc1,
                                              const float* __restrict__ Wc2, const float* __restrict__ bc2,
                                              const float* __restrict__ Wp1, const float* __restrict__ bp1,
                                              const float* __restrict__ Wp2, const float* __restrict__ bp2,
                                              float* __restrict__ out, int N) {
    __shared__ float sh[4][128];
    const int lane = threadIdx.x & 63, wave = threadIdx.x >> 6;
    const int i = blockIdx.x * 4 + wave;
    if (i >= N) return;
    float2 hv = *reinterpret_cast<const float2*>(h + (size_t)i * 128 + lane * 2);
    sh[wave][lane * 2] = hv.x; sh[wave][lane * 2 + 1] = hv.y;
    float t1 = bc1[lane], t2 = bp1[lane];
    for (int k = 0; k < 128; ++k) {
        float hk = sh[wave][k];
        t1 += hk * Wc1[k * 64 + lane];
        t2 += hk * Wp1[k * 64 + lane];
    }
    t1 = fmaxf(t1, 0.f); t2 = fmaxf(t2, 0.f);
    float c[5];
#pragma unroll
    for (int cc = 0; cc < 5; ++cc) {
        float vv = t1 * Wc2[lane * 5 + cc];
        for (int o = 1; o < 64; o <<= 1) vv += __shfl_xor(vv, o, 64);
        c[cc] = vv;
    }
    float pv = t2 * Wp2[lane];
    for (int o = 1; o < 64; o <<= 1) pv += __shfl_xor(pv, o, 64);
    if (lane == 0) {
#pragma unroll
        for (int cc = 0; cc < 5; ++cc) out[(size_t)i * 5 + cc] = c[cc] + bc2[cc];
        out[(size_t)N * 5 + i] = 1.f / (1.f + expf(-(pv + bp2[0])));
    }
}

extern "C" void kernel_launch(void* const* d_in, const int* in_sizes, int n_in,
                              void* d_out, int out_size, void* d_ws, size_t ws_size,
                              hipStream_t stream) {
    const float* node_feats = (const float*)d_in[0];
    const int*   edge_index = (const int*)d_in[1];
    const float* edge_feats = (const float*)d_in[2];
    const float* W_in = (const float*)d_in[3];
    const float* b_in = (const float*)d_in[4];
    const float* W_m1 = (const float*)d_in[5];
    const float* b_m1 = (const float*)d_in[6];
    const float* W_m2 = (const float*)d_in[7];
    const float* b_m2 = (const float*)d_in[8];
    const float* W_z  = (const float*)d_in[9];
    const float* b_z  = (const float*)d_in[10];
    const float* W_r  = (const float*)d_in[11];
    const float* b_r  = (const float*)d_in[12];
    const float* W_h  = (const float*)d_in[13];
    const float* b_h  = (const float*)d_in[14];
    const float* ln_s = (const float*)d_in[15];
    const float* ln_b = (const float*)d_in[16];
    const float* W_c1 = (const float*)d_in[17];
    const float* b_c1 = (const float*)d_in[18];
    const float* W_c2 = (const float*)d_in[19];
    const float* b_c2 = (const float*)d_in[20];
    const float* W_p1 = (const float*)d_in[21];
    const float* b_p1 = (const float*)d_in[22];
    const float* W_p2 = (const float*)d_in[23];
    const float* b_p2 = (const float*)d_in[24];

    const int N = in_sizes[0] / 8;
    const int E = in_sizes[2] / 4;

    char* ws = (char*)d_ws;
    size_t off = 0;
    auto alloc = [&](size_t bytes) { size_t p = off; off = (off + bytes + 255) & ~(size_t)255; return p; };
    const size_t o_hf = alloc((size_t)N * 128 * 4);   // f32 h
    const size_t o_X  = alloc((size_t)N * 256 * 4);   // f32 [Xs|Xd] ; Xd<-T ; Xs<-agg
    const size_t o_pk = alloc((size_t)STEPS * 294912 * 2);
    const size_t o_deg = alloc((size_t)N * 4);
    const size_t o_off = alloc((size_t)(N + 1) * 4);
    const size_t o_cur = alloc((size_t)N * 4);
    const size_t o_ex  = alloc((size_t)N * 4);
    const size_t o_bs  = alloc(1024 * 4);
    const size_t o_be  = alloc(1024 * 4);
    const size_t o_ss  = alloc((size_t)E * 4);
    const size_t o_ei  = alloc((size_t)E * 4);

    if (off > ws_size) {  // fail cleanly (diagnosable) instead of faulting
        hipMemsetAsync(d_out, 0, (size_t)out_size * 4, stream);
        return;
    }

    float* hf = (float*)(ws + o_hf);
    float* X  = (float*)(ws + o_X);

    // ---- CSR by dst ----
    hipMemsetAsync(ws + o_deg, 0, (size_t)N * 4, stream);
    hipMemsetAsync(ws + o_cur, 0, (size_t)N * 4, stream);
    hist_k<<<(E + 255) / 256, 256, 0, stream>>>(edge_index + E, (int*)(ws + o_deg), E);
    const int nb1 = (N + 1023) / 1024;
    scan1_k<<<nb1, 256, 0, stream>>>((int*)(ws + o_deg), (int*)(ws + o_ex), (int*)(ws + o_bs), N);
    scan2_k<<<1, 1024, 0, stream>>>((int*)(ws + o_bs), (int*)(ws + o_be), nb1);
    scan3_k<<<(N + 1 + 255) / 256, 256, 0, stream>>>((int*)(ws + o_ex), (int*)(ws + o_be),
                                                     (int*)(ws + o_off), N, E);
    scatter_k<<<(E + 255) / 256, 256, 0, stream>>>(edge_index, edge_index + E, (int*)(ws + o_off),
                                                   (int*)(ws + o_cur), (int*)(ws + o_ss),
                                                   (int*)(ws + o_ei), E);
    // ---- pack weights (hi+lo planes) ----
    pack_k<<<dim3(16, STEPS, 5), 256, 0, stream>>>(W_m1, W_m2, W_z, W_r, W_h,
                                                   (unsigned short*)(ws + o_pk));
    // ---- input projection (f32) ----
    proj_k<<<(N + 3) / 4, 256, 0, stream>>>(node_feats, W_in, b_in, hf, N);

    const int MB = (N + 127) / 128;

    for (int s = 0; s < STEPS; ++s) {
        const unsigned short* pk = (const unsigned short*)(ws + o_pk) + (size_t)s * 294912;
        const unsigned short* pkL = pk + 147456;
        // X = [h@W1_src | h@W1_dst]  (f32)
        gemm_k<0><<<dim3(MB, 2), 256, 0, stream>>>(hf, 128, pk, pkL, nullptr, nullptr,
                                                   X, 256, N, 128);
        // T[v] = sum relu(Xs + Xd + ef@Wef + b1) -> X[:,128:256]
        edge_k<<<(N + 3) / 4, 256, 0, stream>>>(X, (int*)(ws + o_off), (int*)(ws + o_ss),
                                                (int*)(ws + o_ei), (const float4*)edge_feats,
                                                W_m1 + (size_t)s * 33280, b_m1 + (size_t)s * 128, N);
        // agg = T@W2 + deg*b_m2 -> X[:,0:128]
        gemm_k<1><<<dim3(MB, 1), 256, 0, stream>>>(X + 128, 256, pk + 32768, pkL + 32768,
                                                   b_m2 + (size_t)s * 128, (int*)(ws + o_deg),
                                                   X, 256, N, 128);
        // fused gates + candidate + blend + LN (in-place hf)
        zrh_k<<<MB, 256, 0, stream>>>(hf, X,
                                      pk + 49152, pkL + 49152,     // Wz hi/lo
                                      pk + 81920, pkL + 81920,     // Wr hi/lo
                                      pk + 114688, pkL + 114688,   // Wh hi/lo
                                      b_z + (size_t)s * 128, b_r + (size_t)s * 128,
                                      b_h + (size_t)s * 128,
                                      ln_s + (size_t)s * 128, ln_b + (size_t)s * 128, N);
    }

    head_k<<<(N + 3) / 4, 256, 0, stream>>>(hf, W_c1, b_c1, W_c2, b_c2, W_p1, b_p1, W_p2, b_p2,
                                            (float*)d_out, N);
}

// Round 7
// 3944.580 us; speedup vs baseline: 1.0726x; 1.0726x over previous
//
#include <hip/hip_runtime.h>

#define STEPS 6

typedef __attribute__((ext_vector_type(8))) short short8;
typedef __attribute__((ext_vector_type(4))) float f32x4;
typedef __attribute__((ext_vector_type(8))) float f32x8;

__device__ __forceinline__ float bf2f(unsigned int u16) {
    union { unsigned int u; float f; } v; v.u = u16 << 16; return v.f;
}
__device__ __forceinline__ unsigned int f2bf(float x) {
    union { float f; unsigned int u; } v; v.f = x;
    unsigned int r = v.u + 0x7fffu + ((v.u >> 16) & 1u);
    return r >> 16;
}
__device__ __forceinline__ void decompv(const f32x8& v, short8& hi, short8& lo) {
#pragma unroll
    for (int j = 0; j < 8; ++j) {
        float x = v[j];
        unsigned int h = f2bf(x);
        hi[j] = (short)h;
        lo[j] = (short)f2bf(x - bf2f(h));
    }
}
// async global->LDS, 16B per lane: LDS dst = uniform base + lane*16
__device__ __forceinline__ void gl_lds16(const void* g, void* s) {
    __builtin_amdgcn_global_load_lds(
        (const __attribute__((address_space(1))) unsigned int*)g,
        (__attribute__((address_space(3))) unsigned int*)s, 16, 0, 0);
}

// ---------------- CSR build ----------------
__global__ __launch_bounds__(256) void hist_k(const int* __restrict__ dst, int* __restrict__ deg, int E) {
    int e = blockIdx.x * 256 + threadIdx.x;
    if (e < E) atomicAdd(&deg[dst[e]], 1);
}

__global__ __launch_bounds__(256) void scan1_k(const int* __restrict__ in, int* __restrict__ ex,
                                               int* __restrict__ bs, int N) {
    __shared__ int sd[256];
    int t = threadIdx.x;
    int base = blockIdx.x * 1024 + t * 4;
    int v[4]; int s = 0;
#pragma unroll
    for (int i = 0; i < 4; ++i) { int idx = base + i; v[i] = idx < N ? in[idx] : 0; s += v[i]; }
    sd[t] = s; __syncthreads();
    for (int o = 1; o < 256; o <<= 1) {
        int x = (t >= o) ? sd[t - o] : 0;
        __syncthreads();
        sd[t] += x;
        __syncthreads();
    }
    int run = sd[t] - s;
#pragma unroll
    for (int i = 0; i < 4; ++i) { int idx = base + i; if (idx < N) ex[idx] = run; run += v[i]; }
    if (t == 255) bs[blockIdx.x] = sd[255];
}

__global__ __launch_bounds__(1024) void scan2_k(const int* __restrict__ bs, int* __restrict__ be, int nb) {
    __shared__ int sd[1024];
    int t = threadIdx.x;
    int v = (t < nb) ? bs[t] : 0;
    sd[t] = v; __syncthreads();
    for (int o = 1; o < 1024; o <<= 1) {
        int x = (t >= o) ? sd[t - o] : 0;
        __syncthreads();
        sd[t] += x;
        __syncthreads();
    }
    if (t < nb) be[t] = sd[t] - v;
}

__global__ __launch_bounds__(256) void scan3_k(const int* __restrict__ ex, const int* __restrict__ be,
                                               int* __restrict__ offs, int N, int E) {
    int i = blockIdx.x * 256 + threadIdx.x;
    if (i < N) offs[i] = ex[i] + be[i >> 10];
    if (i == N) offs[N] = E;
}

__global__ __launch_bounds__(256) void scatter_k(const int* __restrict__ src, const int* __restrict__ dst,
                                                 const int* __restrict__ offs,
                                                 int* __restrict__ cursor, int* __restrict__ src_sorted,
                                                 int* __restrict__ eid_sorted, int E) {
    int e = blockIdx.x * 256 + threadIdx.x;
    if (e >= E) return;
    int d = dst[e];
    int pos = offs[d] + atomicAdd(&cursor[d], 1);
    src_sorted[pos] = src[e];
    eid_sorted[pos] = e;
}

// ---------------- weight packing: hi+lo bf16 planes, B-fragment order ----------------
// frag addr: ((ct*KS + ks)*64 + lane)*8 + j ; k = ks*32 + (lane>>4)*8 + j, col = ct*16 + (lane&15)
// per-step (stride 294912 elems): hi plane at +0, lo plane at +147456
// mat offsets (elems): W1:0 (32768), W2:32768 (16384), Wz:49152, Wr:81920, Wh:114688
__global__ __launch_bounds__(256) void pack_k(const float* __restrict__ W_m1, const float* __restrict__ W_m2,
                                              const float* __restrict__ W_z, const float* __restrict__ W_r,
                                              const float* __restrict__ W_h, unsigned short* __restrict__ packed) {
    const int s = blockIdx.y, mat = blockIdx.z;
    const int t = blockIdx.x * 256 + threadIdx.x;
    const int lane = t & 63;
    int KS, width; size_t moff;
    if (mat == 0)      { KS = 4; width = 256; moff = 0; }
    else if (mat == 1) { KS = 4; width = 128; moff = 32768; }
    else if (mat == 2) { KS = 8; width = 128; moff = 49152; }
    else if (mat == 3) { KS = 8; width = 128; moff = 81920; }
    else               { KS = 8; width = 128; moff = 114688; }
    const int total = (width >> 4) * KS * 64;
    if (t >= total) return;
    const int ks = (t >> 6) % KS;
    const int ct = (t >> 6) / KS;
    const int col = ct * 16 + (lane & 15);
    const int kb = ks * 32 + (lane >> 4) * 8;
    unsigned short* dh = packed + (size_t)s * 294912 + moff;
    unsigned short* dl = dh + 147456;
#pragma unroll
    for (int j = 0; j < 8; ++j) {
        const int k = kb + j;
        float v;
        if (mat == 0) {
            const float* W = W_m1 + (size_t)s * 260 * 128;
            v = (col < 128) ? W[k * 128 + col] : W[(128 + k) * 128 + (col - 128)];
        } else if (mat == 1) {
            v = W_m2[(size_t)s * 16384 + k * 128 + col];
        } else if (mat == 2) {
            v = W_z[(size_t)s * 32768 + k * 128 + col];
        } else if (mat == 3) {
            v = W_r[(size_t)s * 32768 + k * 128 + col];
        } else {
            v = W_h[(size_t)s * 32768 + k * 128 + col];
        }
        unsigned int hb = f2bf(v);
        dh[(size_t)t * 8 + j] = (unsigned short)hb;
        dl[(size_t)t * 8 + j] = (unsigned short)f2bf(v - bf2f(hb));
    }
}

// ---------------- input projection -> f32 h ----------------
__global__ __launch_bounds__(256) void proj_k(const float* __restrict__ nf, const float* __restrict__ Win,
                                              const float* __restrict__ bin,
                                              float* __restrict__ hf, int N) {
    const int lane = threadIdx.x & 63, wave = threadIdx.x >> 6;
    const int i = blockIdx.x * 4 + wave;
    if (i >= N) return;
    const int c0 = lane * 2;
    float a0 = bin[c0], a1 = bin[c0 + 1];
#pragma unroll
    for (int q = 0; q < 8; ++q) {
        float x = nf[(size_t)i * 8 + q];
        a0 += x * Win[q * 128 + c0];
        a1 += x * Win[q * 128 + c0 + 1];
    }
    hf[(size_t)i * 128 + c0] = a0;
    hf[(size_t)i * 128 + c0 + 1] = a1;
}

// ---------------- f32-accurate MFMA GEMM, LDS-staged weights (K=128) ----------------
// MODE 0: X = h@[W1s|W1d] : A=hf lda=128, out=X ldo=256 (cols cgrp*128..)
// MODE 1: agg = T@W2 + deg*b : A=X+128 lda=256, out=X ldo=256 (cols 0:128)
template <int MODE>
__global__ __launch_bounds__(256) void gemm_k(const float* __restrict__ A, int lda,
                                              const unsigned short* __restrict__ pkh,
                                              const unsigned short* __restrict__ pkl,
                                              const float* __restrict__ bias,
                                              const int* __restrict__ deg,
                                              float* __restrict__ out, int ldo,
                                              int Nrows) {
    __shared__ char stg[2][16384];  // 16 lines x 1KB, double-buffered
    const int lane = threadIdx.x & 63;
    const int wave = threadIdx.x >> 6;
    const int l15 = lane & 15, l16 = lane >> 4;
    const int mbase = blockIdx.x * 128 + wave * 32;
    const int cgrp = blockIdx.y;

    int r0 = mbase + l15;      if (r0 >= Nrows) r0 = 0;
    int r1 = mbase + 16 + l15; if (r1 >= Nrows) r1 = 0;
    const float* a0p = A + (size_t)r0 * lda;
    const float* a1p = A + (size_t)r1 * lda;

    f32x4 acc[2][8];
#pragma unroll
    for (int rt = 0; rt < 2; ++rt)
#pragma unroll
        for (int ct = 0; ct < 8; ++ct) acc[rt][ct] = (f32x4){0.f, 0.f, 0.f, 0.f};

    // stage: line = plane*8 + ct (plane0=hi, 1=lo); wave stages 4 lines
    auto STG = [&](int buf, int ks) {
#pragma unroll
        for (int i = 0; i < 4; ++i) {
            const int line = wave * 4 + i;
            const int ct = line & 7;
            const unsigned short* src = (line & 8) ? pkl : pkh;
            gl_lds16((const char*)src + (((size_t)(cgrp * 8 + ct) * 4 + ks) << 10) + lane * 16,
                     &stg[buf][line << 10]);
        }
    };

    STG(0, 0);
    __syncthreads();
    int buf = 0;
    for (int ks = 0; ks < 4; ++ks) {
        if (ks < 3) STG(buf ^ 1, ks + 1);
        const int k = ks * 32 + l16 * 8;
        short8 ahi[2], alo[2];
        decompv(*(const f32x8*)(a0p + k), ahi[0], alo[0]);
        decompv(*(const f32x8*)(a1p + k), ahi[1], alo[1]);
        const char* sb = stg[buf];
#pragma unroll
        for (int ct = 0; ct < 8; ++ct) {
            const short8 wh = *(const short8*)(sb + (ct << 10) + lane * 16);
            const short8 wl = *(const short8*)(sb + ((8 + ct) << 10) + lane * 16);
#pragma unroll
            for (int rt = 0; rt < 2; ++rt) {
                acc[rt][ct] = __builtin_amdgcn_mfma_f32_16x16x32_bf16(ahi[rt], wh, acc[rt][ct], 0, 0, 0);
                acc[rt][ct] = __builtin_amdgcn_mfma_f32_16x16x32_bf16(alo[rt], wh, acc[rt][ct], 0, 0, 0);
                acc[rt][ct] = __builtin_amdgcn_mfma_f32_16x16x32_bf16(ahi[rt], wl, acc[rt][ct], 0, 0, 0);
            }
        }
        __syncthreads();
        buf ^= 1;
    }
#pragma unroll
    for (int rt = 0; rt < 2; ++rt) {
#pragma unroll
        for (int ct = 0; ct < 8; ++ct) {
            const int col = cgrp * 128 + ct * 16 + l15;
#pragma unroll
            for (int r = 0; r < 4; ++r) {
                const int row = mbase + rt * 16 + l16 * 4 + r;
                if (row >= Nrows) continue;
                float v = acc[rt][ct][r];
                if (MODE == 1) v += bias[col] * (float)deg[row];
                out[(size_t)row * ldo + col] = v;
            }
        }
    }
}

// ---------------- fused z,r,rh,hn,blend,LN — LDS-staged weights ----------------
// z = sig([h|agg]@Wz+bz); r = sig([h|agg]@Wr+br); rh = r*h -> X[:,128:256] (T's dead slot);
// hn = tanh([rh|agg]@Wh+bh); h = LN((1-z)h + z*hn)  -- all f32, 3-MFMA scheme.
__global__ __launch_bounds__(256) void zrh_k(float* __restrict__ hf,
                                             float* __restrict__ X,  // [N,256]: 0:128 agg, 128:256 T->rh
                                             const unsigned short* __restrict__ pzh, const unsigned short* __restrict__ pzl,
                                             const unsigned short* __restrict__ prh, const unsigned short* __restrict__ prl,
                                             const unsigned short* __restrict__ phh, const unsigned short* __restrict__ phl,
                                             const float* __restrict__ bz, const float* __restrict__ br,
                                             const float* __restrict__ bh,
                                             const float* __restrict__ lns, const float* __restrict__ lnb,
                                             int N) {
    __shared__ char stg[2][32768];  // phase1: 32 lines x 1KB; phase3: 16 lines
    const int lane = threadIdx.x & 63;
    const int wave = threadIdx.x >> 6;
    const int l15 = lane & 15, l16 = lane >> 4;
    const int mbase = blockIdx.x * 128 + wave * 32;

    int r0 = mbase + l15;      if (r0 >= N) r0 = 0;
    int r1 = mbase + 16 + l15; if (r1 >= N) r1 = 0;

    // phase1 A: k<128 -> hf[r,k] ; k>=128 -> agg = X[r, k-128]
    auto aptr1 = [&](int r, int k) -> const float* {
        return (k < 128) ? (hf + (size_t)r * 128 + k) : (X + (size_t)r * 256 + (k - 128));
    };
    // phase3 A: k<128 -> rh = X[r, 128+k] ; k>=128 -> agg = X[r, k-128]
    auto aptr3 = [&](int r, int k) -> const float* {
        return (k < 128) ? (X + (size_t)r * 256 + 128 + k) : (X + (size_t)r * 256 + (k - 128));
    };

    const unsigned short* wsrc1 = (wave == 0) ? pzh : (wave == 1) ? pzl : (wave == 2) ? prh : prl;
    auto STG1 = [&](int buf, int ks) {  // 32 lines: plane(=wave)*8 + ct
#pragma unroll
        for (int i = 0; i < 8; ++i)
            gl_lds16((const char*)wsrc1 + (((size_t)(i * 8 + ks)) << 10) + lane * 16,
                     &stg[buf][(wave * 8 + i) << 10]);
    };
    auto STG3 = [&](int buf, int ks) {  // 16 lines: plane*8 + ct
#pragma unroll
        for (int i = 0; i < 4; ++i) {
            const int line = wave * 4 + i;
            const unsigned short* src = (line & 8) ? phl : phh;
            const int ct = line & 7;
            gl_lds16((const char*)src + (((size_t)(ct * 8 + ks)) << 10) + lane * 16,
                     &stg[buf][line << 10]);
        }
    };

    // ---- phase 1: z_pre, r_pre over K=256 ([h | agg]) ----
    f32x4 zac[2][8], rac[2][8];
#pragma unroll
    for (int rt = 0; rt < 2; ++rt)
#pragma unroll
        for (int ct = 0; ct < 8; ++ct) {
            zac[rt][ct] = (f32x4){0.f, 0.f, 0.f, 0.f};
            rac[rt][ct] = (f32x4){0.f, 0.f, 0.f, 0.f};
        }
    STG1(0, 0);
    f32x8 araw0 = *(const f32x8*)aptr1(r0, l16 * 8);
    f32x8 araw1 = *(const f32x8*)aptr1(r1, l16 * 8);
    __syncthreads();
    int buf = 0;
    for (int ks = 0; ks < 8; ++ks) {
        f32x8 an0, an1;
        if (ks < 7) {
            STG1(buf ^ 1, ks + 1);
            const int kn = (ks + 1) * 32 + l16 * 8;
            an0 = *(const f32x8*)aptr1(r0, kn);
            an1 = *(const f32x8*)aptr1(r1, kn);
        }
        short8 ahi[2], alo[2];
        decompv(araw0, ahi[0], alo[0]);
        decompv(araw1, ahi[1], alo[1]);
        const char* sb = stg[buf];
#pragma unroll
        for (int ct = 0; ct < 8; ++ct) {
            const short8 wzh = *(const short8*)(sb + (ct << 10) + lane * 16);
            const short8 wzl = *(const short8*)(sb + ((8 + ct) << 10) + lane * 16);
            const short8 wrh = *(const short8*)(sb + ((16 + ct) << 10) + lane * 16);
            const short8 wrl = *(const short8*)(sb + ((24 + ct) << 10) + lane * 16);
#pragma unroll
            for (int rt = 0; rt < 2; ++rt) {
                zac[rt][ct] = __builtin_amdgcn_mfma_f32_16x16x32_bf16(ahi[rt], wzh, zac[rt][ct], 0, 0, 0);
                zac[rt][ct] = __builtin_amdgcn_mfma_f32_16x16x32_bf16(alo[rt], wzh, zac[rt][ct], 0, 0, 0);
                zac[rt][ct] = __builtin_amdgcn_mfma_f32_16x16x32_bf16(ahi[rt], wzl, zac[rt][ct], 0, 0, 0);
                rac[rt][ct] = __builtin_amdgcn_mfma_f32_16x16x32_bf16(ahi[rt], wrh, rac[rt][ct], 0, 0, 0);
                rac[rt][ct] = __builtin_amdgcn_mfma_f32_16x16x32_bf16(alo[rt], wrh, rac[rt][ct], 0, 0, 0);
                rac[rt][ct] = __builtin_amdgcn_mfma_f32_16x16x32_bf16(ahi[rt], wrl, rac[rt][ct], 0, 0, 0);
            }
        }
        __syncthreads();
        buf ^= 1;
        araw0 = an0; araw1 = an1;
    }

    // ---- phase 2: z = sigmoid (keep in zac); rh = sigmoid(r)*h -> X[:,128:256] f32 ----
#pragma unroll
    for (int rt = 0; rt < 2; ++rt)
#pragma unroll
        for (int ct = 0; ct < 8; ++ct) {
            const int col = ct * 16 + l15;
#pragma unroll
            for (int r = 0; r < 4; ++r) {
                const int row = mbase + rt * 16 + l16 * 4 + r;
                const size_t idx = (size_t)(row < N ? row : 0) * 128 + col;
                float zp = zac[rt][ct][r] + bz[col];
                zac[rt][ct][r] = 1.f / (1.f + expf(-zp));
                float rp = rac[rt][ct][r] + br[col];
                float rr = 1.f / (1.f + expf(-rp));
                if (row < N) X[(size_t)row * 256 + 128 + col] = rr * hf[idx];
            }
        }

    // ---- phase 3: hn_pre over K=256 ([rh | agg]) ----
    f32x4 hac[2][8];
#pragma unroll
    for (int rt = 0; rt < 2; ++rt)
#pragma unroll
        for (int ct = 0; ct < 8; ++ct) hac[rt][ct] = (f32x4){0.f, 0.f, 0.f, 0.f};
    STG3(0, 0);
    araw0 = *(const f32x8*)aptr3(r0, l16 * 8);
    araw1 = *(const f32x8*)aptr3(r1, l16 * 8);
    __syncthreads();
    buf = 0;
    for (int ks = 0; ks < 8; ++ks) {
        f32x8 an0, an1;
        if (ks < 7) {
            STG3(buf ^ 1, ks + 1);
            const int kn = (ks + 1) * 32 + l16 * 8;
            an0 = *(const f32x8*)aptr3(r0, kn);
            an1 = *(const f32x8*)aptr3(r1, kn);
        }
        short8 ahi[2], alo[2];
        decompv(araw0, ahi[0], alo[0]);
        decompv(araw1, ahi[1], alo[1]);
        const char* sb = stg[buf];
#pragma unroll
        for (int ct = 0; ct < 8; ++ct) {
            const short8 wh = *(const short8*)(sb + (ct << 10) + lane * 16);
            const short8 wl = *(const short8*)(sb + ((8 + ct) << 10) + lane * 16);
#pragma unroll
            for (int rt = 0; rt < 2; ++rt) {
                hac[rt][ct] = __builtin_amdgcn_mfma_f32_16x16x32_bf16(ahi[rt], wh, hac[rt][ct], 0, 0, 0);
                hac[rt][ct] = __builtin_amdgcn_mfma_f32_16x16x32_bf16(alo[rt], wh, hac[rt][ct], 0, 0, 0);
                hac[rt][ct] = __builtin_amdgcn_mfma_f32_16x16x32_bf16(ahi[rt], wl, hac[rt][ct], 0, 0, 0);
            }
        }
        __syncthreads();
        buf ^= 1;
        araw0 = an0; araw1 = an1;
    }

    // ---- phase 4: blend + LayerNorm -> hf ----
#pragma unroll
    for (int rt = 0; rt < 2; ++rt)
#pragma unroll
        for (int ct = 0; ct < 8; ++ct) {
            const int col = ct * 16 + l15;
#pragma unroll
            for (int r = 0; r < 4; ++r) {
                const int row = mbase + rt * 16 + l16 * 4 + r;
                const size_t idx = (size_t)(row < N ? row : 0) * 128 + col;
                float hn = tanhf(hac[rt][ct][r] + bh[col]);
                float zz = zac[rt][ct][r];
                hac[rt][ct][r] = (1.f - zz) * hf[idx] + zz * hn;
            }
        }
#pragma unroll
    for (int rt = 0; rt < 2; ++rt)
#pragma unroll
        for (int r = 0; r < 4; ++r) {
            const int row = mbase + rt * 16 + l16 * 4 + r;
            float s = 0.f, ss = 0.f;
#pragma unroll
            for (int ct = 0; ct < 8; ++ct) {
                float y = hac[rt][ct][r];
                s += y; ss += y * y;
            }
#pragma unroll
            for (int m = 1; m < 16; m <<= 1) {
                s += __shfl_xor(s, m, 64);
                ss += __shfl_xor(ss, m, 64);
            }
            float mean = s * (1.f / 128.f);
            float var = ss * (1.f / 128.f) - mean * mean;
            float inv = rsqrtf(var + 1e-6f);
            if (row < N) {
#pragma unroll
                for (int ct = 0; ct < 8; ++ct) {
                    const int col = ct * 16 + l15;
                    hf[(size_t)row * 128 + col] = (hac[rt][ct][r] - mean) * inv * lns[col] + lnb[col];
                }
            }
        }
}

// ---------------- edge accumulate (f32): T[v] = sum relu(Xs[src]+Xd[v]+ef@Wef+b1) -> X[:,128:256] ----
__global__ __launch_bounds__(256) void edge_k(float* __restrict__ X,
                                              const int* __restrict__ offs,
                                              const int* __restrict__ src_sorted,
                                              const int* __restrict__ eid_sorted,
                                              const float4* __restrict__ ef_all,
                                              const float* __restrict__ Wm1_s,
                                              const float* __restrict__ bm1_s,
                                              int N) {
    const int lane = threadIdx.x & 63, wave = threadIdx.x >> 6;
    const int v = blockIdx.x * 4 + wave;
    if (v >= N) return;
    const int c0 = lane * 2;
    const float base0 = X[(size_t)v * 256 + 128 + c0] + bm1_s[c0];
    const float base1 = X[(size_t)v * 256 + 129 + c0] + bm1_s[c0 + 1];
    const float w0x = Wm1_s[256 * 128 + c0], w0y = Wm1_s[256 * 128 + c0 + 1];
    const float w1x = Wm1_s[257 * 128 + c0], w1y = Wm1_s[257 * 128 + c0 + 1];
    const float w2x = Wm1_s[258 * 128 + c0], w2y = Wm1_s[258 * 128 + c0 + 1];
    const float w3x = Wm1_s[259 * 128 + c0], w3y = Wm1_s[259 * 128 + c0 + 1];
    float acc0 = 0.f, acc1 = 0.f;
    const int beg = offs[v], end = offs[v + 1];
    for (int i = beg; i < end; ++i) {
        int sn = src_sorted[i];
        int eid = eid_sorted[i];
        float4 ef = ef_all[eid];
        float2 xs = *reinterpret_cast<const float2*>(X + (size_t)sn * 256 + c0);
        float e0 = ef.x * w0x + ef.y * w1x + ef.z * w2x + ef.w * w3x;
        float e1 = ef.x * w0y + ef.y * w1y + ef.z * w2y + ef.w * w3y;
        acc0 += fmaxf(xs.x + base0 + e0, 0.f);
        acc1 += fmaxf(xs.y + base1 + e1, 0.f);
    }
    X[(size_t)v * 256 + 128 + c0] = acc0;   // T overwrites Xd (consumed above)
    X[(size_t)v * 256 + 129 + c0] = acc1;
}

// ---------------- heads (f32) ----------------
__global__ __launch_bounds__(256) void head_k(const float* __restrict__ h,
                                              const float* __restrict__ Wc1, const float* __restrict__ bc1,
                                              const float* __restrict__ Wc2, const float* __restrict__ bc2,
                                              const float* __restrict__ Wp1, const float* __restrict__ bp1,
                                              const float* __restrict__ Wp2, const float* __restrict__ bp2,
                                              float* __restrict__ out, int N) {
    __shared__ float sh[4][128];
    const int lane = threadIdx.x & 63, wave = threadIdx.x >> 6;
    const int i = blockIdx.x * 4 + wave;
    if (i >= N) return;
    float2 hv = *reinterpret_cast<const float2*>(h + (size_t)i * 128 + lane * 2);
    sh[wave][lane * 2] = hv.x; sh[wave][lane * 2 + 1] = hv.y;
    float t1 = bc1[lane], t2 = bp1[lane];
    for (int k = 0; k < 128; ++k) {
        float hk = sh[wave][k];
        t1 += hk * Wc1[k * 64 + lane];
        t2 += hk * Wp1[k * 64 + lane];
    }
    t1 = fmaxf(t1, 0.f); t2 = fmaxf(t2, 0.f);
    float c[5];
#pragma unroll
    for (int cc = 0; cc < 5; ++cc) {
        float vv = t1 * Wc2[lane * 5 + cc];
        for (int o = 1; o < 64; o <<= 1) vv += __shfl_xor(vv, o, 64);
        c[cc] = vv;
    }
    float pv = t2 * Wp2[lane];
    for (int o = 1; o < 64; o <<= 1) pv += __shfl_xor(pv, o, 64);
    if (lane == 0) {
#pragma unroll
        for (int cc = 0; cc < 5; ++cc) out[(size_t)i * 5 + cc] = c[cc] + bc2[cc];
        out[(size_t)N * 5 + i] = 1.f / (1.f + expf(-(pv + bp2[0])));
    }
}

extern "C" void kernel_launch(void* const* d_in, const int* in_sizes, int n_in,
                              void* d_out, int out_size, void* d_ws, size_t ws_size,
                              hipStream_t stream) {
    const float* node_feats = (const float*)d_in[0];
    const int*   edge_index = (const int*)d_in[1];
    const float* edge_feats = (const float*)d_in[2];
    const float* W_in = (const float*)d_in[3];
    const float* b_in = (const float*)d_in[4];
    const float* W_m1 = (const float*)d_in[5];
    const float* b_m1 = (const float*)d_in[6];
    const float* W_m2 = (const float*)d_in[7];
    const float* b_m2 = (const float*)d_in[8];
    const float* W_z  = (const float*)d_in[9];
    const float* b_z  = (const float*)d_in[10];
    const float* W_r  = (const float*)d_in[11];
    const float* b_r  = (const float*)d_in[12];
    const float* W_h  = (const float*)d_in[13];
    const float* b_h  = (const float*)d_in[14];
    const float* ln_s = (const float*)d_in[15];
    const float* ln_b = (const float*)d_in[16];
    const float* W_c1 = (const float*)d_in[17];
    const float* b_c1 = (const float*)d_in[18];
    const float* W_c2 = (const float*)d_in[19];
    const float* b_c2 = (const float*)d_in[20];
    const float* W_p1 = (const float*)d_in[21];
    const float* b_p1 = (const float*)d_in[22];
    const float* W_p2 = (const float*)d_in[23];
    const float* b_p2 = (const float*)d_in[24];

    const int N = in_sizes[0] / 8;
    const int E = in_sizes[2] / 4;

    char* ws = (char*)d_ws;
    size_t off = 0;
    auto alloc = [&](size_t bytes) { size_t p = off; off = (off + bytes + 255) & ~(size_t)255; return p; };
    const size_t o_hf = alloc((size_t)N * 128 * 4);   // f32 h
    const size_t o_X  = alloc((size_t)N * 256 * 4);   // f32 [agg|Xd->T->rh]
    const size_t o_pk = alloc((size_t)STEPS * 294912 * 2);
    const size_t o_deg = alloc((size_t)N * 4);
    const size_t o_off = alloc((size_t)(N + 1) * 4);
    const size_t o_cur = alloc((size_t)N * 4);
    const size_t o_ex  = alloc((size_t)N * 4);
    const size_t o_bs  = alloc(1024 * 4);
    const size_t o_be  = alloc(1024 * 4);
    const size_t o_ss  = alloc((size_t)E * 4);
    const size_t o_ei  = alloc((size_t)E * 4);

    if (off > ws_size) {  // fail cleanly (diagnosable) instead of faulting
        hipMemsetAsync(d_out, 0, (size_t)out_size * 4, stream);
        return;
    }

    float* hf = (float*)(ws + o_hf);
    float* X  = (float*)(ws + o_X);

    // ---- CSR by dst ----
    hipMemsetAsync(ws + o_deg, 0, (size_t)N * 4, stream);
    hipMemsetAsync(ws + o_cur, 0, (size_t)N * 4, stream);
    hist_k<<<(E + 255) / 256, 256, 0, stream>>>(edge_index + E, (int*)(ws + o_deg), E);
    const int nb1 = (N + 1023) / 1024;
    scan1_k<<<nb1, 256, 0, stream>>>((int*)(ws + o_deg), (int*)(ws + o_ex), (int*)(ws + o_bs), N);
    scan2_k<<<1, 1024, 0, stream>>>((int*)(ws + o_bs), (int*)(ws + o_be), nb1);
    scan3_k<<<(N + 1 + 255) / 256, 256, 0, stream>>>((int*)(ws + o_ex), (int*)(ws + o_be),
                                                     (int*)(ws + o_off), N, E);
    scatter_k<<<(E + 255) / 256, 256, 0, stream>>>(edge_index, edge_index + E, (int*)(ws + o_off),
                                                   (int*)(ws + o_cur), (int*)(ws + o_ss),
                                                   (int*)(ws + o_ei), E);
    // ---- pack weights (hi+lo planes) ----
    pack_k<<<dim3(16, STEPS, 5), 256, 0, stream>>>(W_m1, W_m2, W_z, W_r, W_h,
                                                   (unsigned short*)(ws + o_pk));
    // ---- input projection (f32) ----
    proj_k<<<(N + 3) / 4, 256, 0, stream>>>(node_feats, W_in, b_in, hf, N);

    const int MB = (N + 127) / 128;

    for (int s = 0; s < STEPS; ++s) {
        const unsigned short* pk = (const unsigned short*)(ws + o_pk) + (size_t)s * 294912;
        const unsigned short* pkL = pk + 147456;
        // X = [h@W1_src | h@W1_dst]  (f32)
        gemm_k<0><<<dim3(MB, 2), 256, 0, stream>>>(hf, 128, pk, pkL, nullptr, nullptr,
                                                   X, 256, N);
        // T[v] = sum relu(Xs + Xd + ef@Wef + b1) -> X[:,128:256]
        edge_k<<<(N + 3) / 4, 256, 0, stream>>>(X, (int*)(ws + o_off), (int*)(ws + o_ss),
                                                (int*)(ws + o_ei), (const float4*)edge_feats,
                                                W_m1 + (size_t)s * 33280, b_m1 + (size_t)s * 128, N);
        // agg = T@W2 + deg*b_m2 -> X[:,0:128]
        gemm_k<1><<<dim3(MB, 1), 256, 0, stream>>>(X + 128, 256, pk + 32768, pkL + 32768,
                                                   b_m2 + (size_t)s * 128, (int*)(ws + o_deg),
                                                   X, 256, N);
        // fused gates + candidate + blend + LN (in-place hf; rh via X[:,128:256])
        zrh_k<<<MB, 256, 0, stream>>>(hf, X,
                                      pk + 49152, pkL + 49152,     // Wz hi/lo
                                      pk + 81920, pkL + 81920,     // Wr hi/lo
                                      pk + 114688, pkL + 114688,   // Wh hi/lo
                                      b_z + (size_t)s * 128, b_r + (size_t)s * 128,
                                      b_h + (size_t)s * 128,
                                      ln_s + (size_t)s * 128, ln_b + (size_t)s * 128, N);
    }

    head_k<<<(N + 3) / 4, 256, 0, stream>>>(hf, W_c1, b_c1, W_c2, b_c2, W_p1, b_p1, W_p2, b_p2,
                                            (float*)d_out, N);
}

// Round 8
// 3841.227 us; speedup vs baseline: 1.1015x; 1.0269x over previous
//
#include <hip/hip_runtime.h>

#define STEPS 6

typedef __attribute__((ext_vector_type(8))) short short8;
typedef __attribute__((ext_vector_type(4))) float f32x4;
typedef __attribute__((ext_vector_type(8))) float f32x8;

__device__ __forceinline__ float bf2f(unsigned int u16) {
    union { unsigned int u; float f; } v; v.u = u16 << 16; return v.f;
}
__device__ __forceinline__ unsigned int f2bf(float x) {
    union { float f; unsigned int u; } v; v.f = x;
    unsigned int r = v.u + 0x7fffu + ((v.u >> 16) & 1u);
    return r >> 16;
}
__device__ __forceinline__ void decompv(const f32x8& v, short8& hi, short8& lo) {
#pragma unroll
    for (int j = 0; j < 8; ++j) {
        float x = v[j];
        unsigned int h = f2bf(x);
        hi[j] = (short)h;
        lo[j] = (short)f2bf(x - bf2f(h));
    }
}
// async global->LDS, 16B per lane: LDS dst = uniform base + lane*16
__device__ __forceinline__ void gl_lds16(const void* g, void* s) {
    __builtin_amdgcn_global_load_lds(
        (const __attribute__((address_space(1))) unsigned int*)g,
        (__attribute__((address_space(3))) unsigned int*)s, 16, 0, 0);
}

// ---------------- CSR build ----------------
__global__ __launch_bounds__(256) void hist_k(const int* __restrict__ dst, int* __restrict__ deg, int E) {
    int e = blockIdx.x * 256 + threadIdx.x;
    if (e < E) atomicAdd(&deg[dst[e]], 1);
}

__global__ __launch_bounds__(256) void scan1_k(const int* __restrict__ in, int* __restrict__ ex,
                                               int* __restrict__ bs, int N) {
    __shared__ int sd[256];
    int t = threadIdx.x;
    int base = blockIdx.x * 1024 + t * 4;
    int v[4]; int s = 0;
#pragma unroll
    for (int i = 0; i < 4; ++i) { int idx = base + i; v[i] = idx < N ? in[idx] : 0; s += v[i]; }
    sd[t] = s; __syncthreads();
    for (int o = 1; o < 256; o <<= 1) {
        int x = (t >= o) ? sd[t - o] : 0;
        __syncthreads();
        sd[t] += x;
        __syncthreads();
    }
    int run = sd[t] - s;
#pragma unroll
    for (int i = 0; i < 4; ++i) { int idx = base + i; if (idx < N) ex[idx] = run; run += v[i]; }
    if (t == 255) bs[blockIdx.x] = sd[255];
}

__global__ __launch_bounds__(1024) void scan2_k(const int* __restrict__ bs, int* __restrict__ be, int nb) {
    __shared__ int sd[1024];
    int t = threadIdx.x;
    int v = (t < nb) ? bs[t] : 0;
    sd[t] = v; __syncthreads();
    for (int o = 1; o < 1024; o <<= 1) {
        int x = (t >= o) ? sd[t - o] : 0;
        __syncthreads();
        sd[t] += x;
        __syncthreads();
    }
    if (t < nb) be[t] = sd[t] - v;
}

__global__ __launch_bounds__(256) void scan3_k(const int* __restrict__ ex, const int* __restrict__ be,
                                               int* __restrict__ offs, int N, int E) {
    int i = blockIdx.x * 256 + threadIdx.x;
    if (i < N) offs[i] = ex[i] + be[i >> 10];
    if (i == N) offs[N] = E;
}

__global__ __launch_bounds__(256) void scatter_k(const int* __restrict__ src, const int* __restrict__ dst,
                                                 const int* __restrict__ offs,
                                                 int* __restrict__ cursor, int* __restrict__ src_sorted,
                                                 int* __restrict__ eid_sorted, int E) {
    int e = blockIdx.x * 256 + threadIdx.x;
    if (e >= E) return;
    int d = dst[e];
    int pos = offs[d] + atomicAdd(&cursor[d], 1);
    src_sorted[pos] = src[e];
    eid_sorted[pos] = e;
}

// ---------------- weight packing: hi+lo bf16 planes, B-fragment order ----------------
// frag addr: ((ct*KS + ks)*64 + lane)*8 + j ; k = ks*32 + (lane>>4)*8 + j, col = ct*16 + (lane&15)
// per-step (stride 294912 elems): hi plane at +0, lo plane at +147456
// mat offsets (elems): W1:0 (32768), W2:32768 (16384), Wz:49152, Wr:81920, Wh:114688
__global__ __launch_bounds__(256) void pack_k(const float* __restrict__ W_m1, const float* __restrict__ W_m2,
                                              const float* __restrict__ W_z, const float* __restrict__ W_r,
                                              const float* __restrict__ W_h, unsigned short* __restrict__ packed) {
    const int s = blockIdx.y, mat = blockIdx.z;
    const int t = blockIdx.x * 256 + threadIdx.x;
    const int lane = t & 63;
    int KS, width; size_t moff;
    if (mat == 0)      { KS = 4; width = 256; moff = 0; }
    else if (mat == 1) { KS = 4; width = 128; moff = 32768; }
    else if (mat == 2) { KS = 8; width = 128; moff = 49152; }
    else if (mat == 3) { KS = 8; width = 128; moff = 81920; }
    else               { KS = 8; width = 128; moff = 114688; }
    const int total = (width >> 4) * KS * 64;
    if (t >= total) return;
    const int ks = (t >> 6) % KS;
    const int ct = (t >> 6) / KS;
    const int col = ct * 16 + (lane & 15);
    const int kb = ks * 32 + (lane >> 4) * 8;
    unsigned short* dh = packed + (size_t)s * 294912 + moff;
    unsigned short* dl = dh + 147456;
#pragma unroll
    for (int j = 0; j < 8; ++j) {
        const int k = kb + j;
        float v;
        if (mat == 0) {
            const float* W = W_m1 + (size_t)s * 260 * 128;
            v = (col < 128) ? W[k * 128 + col] : W[(128 + k) * 128 + (col - 128)];
        } else if (mat == 1) {
            v = W_m2[(size_t)s * 16384 + k * 128 + col];
        } else if (mat == 2) {
            v = W_z[(size_t)s * 32768 + k * 128 + col];
        } else if (mat == 3) {
            v = W_r[(size_t)s * 32768 + k * 128 + col];
        } else {
            v = W_h[(size_t)s * 32768 + k * 128 + col];
        }
        unsigned int hb = f2bf(v);
        dh[(size_t)t * 8 + j] = (unsigned short)hb;
        dl[(size_t)t * 8 + j] = (unsigned short)f2bf(v - bf2f(hb));
    }
}

// ---------------- input projection -> f32 h ----------------
__global__ __launch_bounds__(256) void proj_k(const float* __restrict__ nf, const float* __restrict__ Win,
                                              const float* __restrict__ bin,
                                              float* __restrict__ hf, int N) {
    const int lane = threadIdx.x & 63, wave = threadIdx.x >> 6;
    const int i = blockIdx.x * 4 + wave;
    if (i >= N) return;
    const int c0 = lane * 2;
    float a0 = bin[c0], a1 = bin[c0 + 1];
#pragma unroll
    for (int q = 0; q < 8; ++q) {
        float x = nf[(size_t)i * 8 + q];
        a0 += x * Win[q * 128 + c0];
        a1 += x * Win[q * 128 + c0 + 1];
    }
    hf[(size_t)i * 128 + c0] = a0;
    hf[(size_t)i * 128 + c0 + 1] = a1;
}

// ---------------- f32-accurate MFMA GEMM, LDS-staged weights (K=128) ----------------
// MODE 0: X = h@[W1s|W1d] : A=hf lda=128, out=X ldo=256 (cols cgrp*128..)
// MODE 1: agg = T@W2 + deg*b : A=X+128 lda=256, out=X ldo=256 (cols 0:128)
template <int MODE>
__global__ __launch_bounds__(256, 3) void gemm_k(const float* __restrict__ A, int lda,
                                                 const unsigned short* __restrict__ pkh,
                                                 const unsigned short* __restrict__ pkl,
                                                 const float* __restrict__ bias,
                                                 const int* __restrict__ deg,
                                                 float* __restrict__ out, int ldo,
                                                 int Nrows) {
    __shared__ char stg[2][16384];  // 16 lines x 1KB, double-buffered
    const int lane = threadIdx.x & 63;
    const int wave = threadIdx.x >> 6;
    const int l15 = lane & 15, l16 = lane >> 4;
    const int mbase = blockIdx.x * 128 + wave * 32;
    const int cgrp = blockIdx.y;

    int r0 = mbase + l15;      if (r0 >= Nrows) r0 = 0;
    int r1 = mbase + 16 + l15; if (r1 >= Nrows) r1 = 0;
    const float* a0p = A + (size_t)r0 * lda;
    const float* a1p = A + (size_t)r1 * lda;

    f32x4 acc[2][8];
#pragma unroll
    for (int rt = 0; rt < 2; ++rt)
#pragma unroll
        for (int ct = 0; ct < 8; ++ct) acc[rt][ct] = (f32x4){0.f, 0.f, 0.f, 0.f};

    // stage: line = plane*8 + ct (plane0=hi, 1=lo); wave stages 4 lines
    auto STG = [&](int buf, int ks) {
#pragma unroll
        for (int i = 0; i < 4; ++i) {
            const int line = wave * 4 + i;
            const int ct = line & 7;
            const unsigned short* src = (line & 8) ? pkl : pkh;
            gl_lds16((const char*)src + (((size_t)(cgrp * 8 + ct) * 4 + ks) << 10) + lane * 16,
                     &stg[buf][line << 10]);
        }
    };

    STG(0, 0);
    __syncthreads();
    int buf = 0;
    for (int ks = 0; ks < 4; ++ks) {
        if (ks < 3) STG(buf ^ 1, ks + 1);
        const int k = ks * 32 + l16 * 8;
        short8 ahi[2], alo[2];
        decompv(*(const f32x8*)(a0p + k), ahi[0], alo[0]);
        decompv(*(const f32x8*)(a1p + k), ahi[1], alo[1]);
        const char* sb = stg[buf];
#pragma unroll
        for (int ct = 0; ct < 8; ++ct) {
            const short8 wh = *(const short8*)(sb + (ct << 10) + lane * 16);
            const short8 wl = *(const short8*)(sb + ((8 + ct) << 10) + lane * 16);
#pragma unroll
            for (int rt = 0; rt < 2; ++rt) {
                acc[rt][ct] = __builtin_amdgcn_mfma_f32_16x16x32_bf16(ahi[rt], wh, acc[rt][ct], 0, 0, 0);
                acc[rt][ct] = __builtin_amdgcn_mfma_f32_16x16x32_bf16(alo[rt], wh, acc[rt][ct], 0, 0, 0);
                acc[rt][ct] = __builtin_amdgcn_mfma_f32_16x16x32_bf16(ahi[rt], wl, acc[rt][ct], 0, 0, 0);
            }
        }
        __syncthreads();
        buf ^= 1;
    }
#pragma unroll
    for (int rt = 0; rt < 2; ++rt) {
#pragma unroll
        for (int ct = 0; ct < 8; ++ct) {
            const int col = cgrp * 128 + ct * 16 + l15;
#pragma unroll
            for (int r = 0; r < 4; ++r) {
                const int row = mbase + rt * 16 + l16 * 4 + r;
                if (row >= Nrows) continue;
                float v = acc[rt][ct][r];
                if (MODE == 1) v += bias[col] * (float)deg[row];
                out[(size_t)row * ldo + col] = v;
            }
        }
    }
}

// ---------------- fused z,r,rh,hn,blend,LN ----------------
// z = sig([h|agg]@Wz+bz); r = sig([h|agg]@Wr+br); rh = r*h kept in LDS (swizzled f32);
// hn = tanh([rh|agg]@Wh+bh); h = LN((1-z)h + z*hn)  -- all f32, 3-MFMA scheme.
__global__ __launch_bounds__(256) void zrh_k(float* __restrict__ hf,
                                             const float* __restrict__ X,  // [N,256]: 0:128 agg
                                             const unsigned short* __restrict__ pzh, const unsigned short* __restrict__ pzl,
                                             const unsigned short* __restrict__ prh, const unsigned short* __restrict__ prl,
                                             const unsigned short* __restrict__ phh, const unsigned short* __restrict__ phl,
                                             const float* __restrict__ bz, const float* __restrict__ br,
                                             const float* __restrict__ bh,
                                             const float* __restrict__ lns, const float* __restrict__ lnb,
                                             int N) {
    __shared__ char stg[2][32768];   // phase1: Wz/Wr dbuf (32 lines x 1KB); phase2/3: rh f32 [4][32][128] swz
    __shared__ char wstg[16384];     // phase3: Wh single-buffer (16 lines x 1KB)
    float* rhs = reinterpret_cast<float*>(stg);
    const int lane = threadIdx.x & 63;
    const int wave = threadIdx.x >> 6;
    const int l15 = lane & 15, l16 = lane >> 4;
    const int mbase = blockIdx.x * 128 + wave * 32;

    int r0 = mbase + l15;      if (r0 >= N) r0 = 0;
    int r1 = mbase + 16 + l15; if (r1 >= N) r1 = 0;

    // phase1 A: k<128 -> hf[r,k] ; k>=128 -> agg = X[r, k-128]
    auto aptr1 = [&](int r, int k) -> const float* {
        return (k < 128) ? (hf + (size_t)r * 128 + k) : (X + (size_t)r * 256 + (k - 128));
    };

    const unsigned short* wsrc1 = (wave == 0) ? pzh : (wave == 1) ? pzl : (wave == 2) ? prh : prl;
    auto STG1 = [&](int buf, int ks) {  // 32 lines: plane(=wave)*8 + ct
#pragma unroll
        for (int i = 0; i < 8; ++i)
            gl_lds16((const char*)wsrc1 + (((size_t)(i * 8 + ks)) << 10) + lane * 16,
                     &stg[buf][(wave * 8 + i) << 10]);
    };

    // ---- phase 1: z_pre, r_pre over K=256 ([h | agg]) ----
    f32x4 zac[2][8], rac[2][8];
#pragma unroll
    for (int rt = 0; rt < 2; ++rt)
#pragma unroll
        for (int ct = 0; ct < 8; ++ct) {
            zac[rt][ct] = (f32x4){0.f, 0.f, 0.f, 0.f};
            rac[rt][ct] = (f32x4){0.f, 0.f, 0.f, 0.f};
        }
    STG1(0, 0);
    f32x8 araw0 = *(const f32x8*)aptr1(r0, l16 * 8);
    f32x8 araw1 = *(const f32x8*)aptr1(r1, l16 * 8);
    __syncthreads();
    int buf = 0;
    for (int ks = 0; ks < 8; ++ks) {
        f32x8 an0, an1;
        if (ks < 7) {
            STG1(buf ^ 1, ks + 1);
            const int kn = (ks + 1) * 32 + l16 * 8;
            an0 = *(const f32x8*)aptr1(r0, kn);
            an1 = *(const f32x8*)aptr1(r1, kn);
        }
        short8 ahi[2], alo[2];
        decompv(araw0, ahi[0], alo[0]);
        decompv(araw1, ahi[1], alo[1]);
        const char* sb = stg[buf];
#pragma unroll
        for (int ct = 0; ct < 8; ++ct) {
            const short8 wzh = *(const short8*)(sb + (ct << 10) + lane * 16);
            const short8 wzl = *(const short8*)(sb + ((8 + ct) << 10) + lane * 16);
            const short8 wrh = *(const short8*)(sb + ((16 + ct) << 10) + lane * 16);
            const short8 wrl = *(const short8*)(sb + ((24 + ct) << 10) + lane * 16);
#pragma unroll
            for (int rt = 0; rt < 2; ++rt) {
                zac[rt][ct] = __builtin_amdgcn_mfma_f32_16x16x32_bf16(ahi[rt], wzh, zac[rt][ct], 0, 0, 0);
                zac[rt][ct] = __builtin_amdgcn_mfma_f32_16x16x32_bf16(alo[rt], wzh, zac[rt][ct], 0, 0, 0);
                zac[rt][ct] = __builtin_amdgcn_mfma_f32_16x16x32_bf16(ahi[rt], wzl, zac[rt][ct], 0, 0, 0);
                rac[rt][ct] = __builtin_amdgcn_mfma_f32_16x16x32_bf16(ahi[rt], wrh, rac[rt][ct], 0, 0, 0);
                rac[rt][ct] = __builtin_amdgcn_mfma_f32_16x16x32_bf16(alo[rt], wrh, rac[rt][ct], 0, 0, 0);
                rac[rt][ct] = __builtin_amdgcn_mfma_f32_16x16x32_bf16(ahi[rt], wrl, rac[rt][ct], 0, 0, 0);
            }
        }
        __syncthreads();
        buf ^= 1;
        araw0 = an0; araw1 = an1;
    }

    // ---- phase 2: z = sigmoid (keep in zac); rh = sigmoid(r)*h -> LDS f32 (32B-group swizzle) ----
#pragma unroll
    for (int rt = 0; rt < 2; ++rt)
#pragma unroll
        for (int ct = 0; ct < 8; ++ct) {
            const int col = ct * 16 + l15;
#pragma unroll
            for (int r = 0; r < 4; ++r) {
                const int rowl = rt * 16 + l16 * 4 + r;
                const int row = mbase + rowl;
                const size_t idx = (size_t)(row < N ? row : 0) * 128 + col;
                float zp = zac[rt][ct][r] + bz[col];
                zac[rt][ct][r] = 1.f / (1.f + expf(-zp));
                float rp = rac[rt][ct][r] + br[col];
                float rr = 1.f / (1.f + expf(-rp));
                rhs[wave * 4096 + rowl * 128 + (((col >> 3) ^ (rowl & 7)) << 3) + (col & 7)] =
                    rr * hf[idx];
            }
        }
    __syncthreads();

    // ---- phase 3: hn_pre over K=256 ([rh(LDS) | agg]) , Wh single-buffered in wstg ----
    f32x4 hac[2][8];
#pragma unroll
    for (int rt = 0; rt < 2; ++rt)
#pragma unroll
        for (int ct = 0; ct < 8; ++ct) hac[rt][ct] = (f32x4){0.f, 0.f, 0.f, 0.f};
    for (int ks = 0; ks < 8; ++ks) {
        // stage Wh[ks]: 16 lines, 4 per wave
#pragma unroll
        for (int i = 0; i < 4; ++i) {
            const int line = wave * 4 + i;
            const unsigned short* src = (line & 8) ? phl : phh;
            const int ct = line & 7;
            gl_lds16((const char*)src + (((size_t)(ct * 8 + ks)) << 10) + lane * 16,
                     &wstg[line << 10]);
        }
        short8 ahi[2], alo[2];
        if (ks < 4) {
#pragma unroll
            for (int rt = 0; rt < 2; ++rt) {
                const int rowl = rt * 16 + l15;
                const int g = ks * 4 + l16;
                const f32x8 v = *(const f32x8*)(rhs + wave * 4096 + rowl * 128 +
                                                ((g ^ (rowl & 7)) << 3));
                decompv(v, ahi[rt], alo[rt]);
            }
        } else {
#pragma unroll
            for (int rt = 0; rt < 2; ++rt) {
                int row = mbase + rt * 16 + l15;
                row = row < N ? row : 0;
                const f32x8 v = *(const f32x8*)(X + (size_t)row * 256 + (ks - 4) * 32 + l16 * 8);
                decompv(v, ahi[rt], alo[rt]);
            }
        }
        __syncthreads();   // Wh staged (vmcnt drain) before reads
        const char* sb = wstg;
#pragma unroll
        for (int ct = 0; ct < 8; ++ct) {
            const short8 wh = *(const short8*)(sb + (ct << 10) + lane * 16);
            const short8 wl = *(const short8*)(sb + ((8 + ct) << 10) + lane * 16);
#pragma unroll
            for (int rt = 0; rt < 2; ++rt) {
                hac[rt][ct] = __builtin_amdgcn_mfma_f32_16x16x32_bf16(ahi[rt], wh, hac[rt][ct], 0, 0, 0);
                hac[rt][ct] = __builtin_amdgcn_mfma_f32_16x16x32_bf16(alo[rt], wh, hac[rt][ct], 0, 0, 0);
                hac[rt][ct] = __builtin_amdgcn_mfma_f32_16x16x32_bf16(ahi[rt], wl, hac[rt][ct], 0, 0, 0);
            }
        }
        __syncthreads();   // before next ks overwrites wstg
    }

    // ---- phase 4: blend + LayerNorm -> hf ----
#pragma unroll
    for (int rt = 0; rt < 2; ++rt)
#pragma unroll
        for (int ct = 0; ct < 8; ++ct) {
            const int col = ct * 16 + l15;
#pragma unroll
            for (int r = 0; r < 4; ++r) {
                const int row = mbase + rt * 16 + l16 * 4 + r;
                const size_t idx = (size_t)(row < N ? row : 0) * 128 + col;
                float hn = tanhf(hac[rt][ct][r] + bh[col]);
                float zz = zac[rt][ct][r];
                hac[rt][ct][r] = (1.f - zz) * hf[idx] + zz * hn;
            }
        }
#pragma unroll
    for (int rt = 0; rt < 2; ++rt)
#pragma unroll
        for (int r = 0; r < 4; ++r) {
            const int row = mbase + rt * 16 + l16 * 4 + r;
            float s = 0.f, ss = 0.f;
#pragma unroll
            for (int ct = 0; ct < 8; ++ct) {
                float y = hac[rt][ct][r];
                s += y; ss += y * y;
            }
#pragma unroll
            for (int m = 1; m < 16; m <<= 1) {
                s += __shfl_xor(s, m, 64);
                ss += __shfl_xor(ss, m, 64);
            }
            float mean = s * (1.f / 128.f);
            float var = ss * (1.f / 128.f) - mean * mean;
            float inv = rsqrtf(var + 1e-6f);
            if (row < N) {
#pragma unroll
                for (int ct = 0; ct < 8; ++ct) {
                    const int col = ct * 16 + l15;
                    hf[(size_t)row * 128 + col] = (hac[rt][ct][r] - mean) * inv * lns[col] + lnb[col];
                }
            }
        }
}

// ---------------- edge accumulate (f32): T[v] = sum relu(Xs[src]+Xd[v]+ef@Wef+b1) -> X[:,128:256] ----
__global__ __launch_bounds__(256) void edge_k(float* __restrict__ X,
                                              const int* __restrict__ offs,
                                              const int* __restrict__ src_sorted,
                                              const int* __restrict__ eid_sorted,
                                              const float4* __restrict__ ef_all,
                                              const float* __restrict__ Wm1_s,
                                              const float* __restrict__ bm1_s,
                                              int N) {
    const int lane = threadIdx.x & 63, wave = threadIdx.x >> 6;
    const int v = blockIdx.x * 4 + wave;
    if (v >= N) return;
    const int c0 = lane * 2;
    const float base0 = X[(size_t)v * 256 + 128 + c0] + bm1_s[c0];
    const float base1 = X[(size_t)v * 256 + 129 + c0] + bm1_s[c0 + 1];
    const float w0x = Wm1_s[256 * 128 + c0], w0y = Wm1_s[256 * 128 + c0 + 1];
    const float w1x = Wm1_s[257 * 128 + c0], w1y = Wm1_s[257 * 128 + c0 + 1];
    const float w2x = Wm1_s[258 * 128 + c0], w2y = Wm1_s[258 * 128 + c0 + 1];
    const float w3x = Wm1_s[259 * 128 + c0], w3y = Wm1_s[259 * 128 + c0 + 1];
    float acc0 = 0.f, acc1 = 0.f;
    const int beg = offs[v], end = offs[v + 1];
    for (int i = beg; i < end; ++i) {
        int sn = src_sorted[i];
        int eid = eid_sorted[i];
        float4 ef = ef_all[eid];
        float2 xs = *reinterpret_cast<const float2*>(X + (size_t)sn * 256 + c0);
        float e0 = ef.x * w0x + ef.y * w1x + ef.z * w2x + ef.w * w3x;
        float e1 = ef.x * w0y + ef.y * w1y + ef.z * w2y + ef.w * w3y;
        acc0 += fmaxf(xs.x + base0 + e0, 0.f);
        acc1 += fmaxf(xs.y + base1 + e1, 0.f);
    }
    X[(size_t)v * 256 + 128 + c0] = acc0;   // T overwrites Xd (consumed above)
    X[(size_t)v * 256 + 129 + c0] = acc1;
}

// ---------------- heads (f32) ----------------
__global__ __launch_bounds__(256) void head_k(const float* __restrict__ h,
                                              const float* __restrict__ Wc1, const float* __restrict__ bc1,
                                              const float* __restrict__ Wc2, const float* __restrict__ bc2,
                                              const float* __restrict__ Wp1, const float* __restrict__ bp1,
                                              const float* __restrict__ Wp2, const float* __restrict__ bp2,
                                              float* __restrict__ out, int N) {
    __shared__ float sh[4][128];
    const int lane = threadIdx.x & 63, wave = threadIdx.x >> 6;
    const int i = blockIdx.x * 4 + wave;
    if (i >= N) return;
    float2 hv = *reinterpret_cast<const float2*>(h + (size_t)i * 128 + lane * 2);
    sh[wave][lane * 2] = hv.x; sh[wave][lane * 2 + 1] = hv.y;
    float t1 = bc1[lane], t2 = bp1[lane];
    for (int k = 0; k < 128; ++k) {
        float hk = sh[wave][k];
        t1 += hk * Wc1[k * 64 + lane];
        t2 += hk * Wp1[k * 64 + lane];
    }
    t1 = fmaxf(t1, 0.f); t2 = fmaxf(t2, 0.f);
    float c[5];
#pragma unroll
    for (int cc = 0; cc < 5; ++cc) {
        float vv = t1 * Wc2[lane * 5 + cc];
        for (int o = 1; o < 64; o <<= 1) vv += __shfl_xor(vv, o, 64);
        c[cc] = vv;
    }
    float pv = t2 * Wp2[lane];
    for (int o = 1; o < 64; o <<= 1) pv += __shfl_xor(pv, o, 64);
    if (lane == 0) {
#pragma unroll
        for (int cc = 0; cc < 5; ++cc) out[(size_t)i * 5 + cc] = c[cc] + bc2[cc];
        out[(size_t)N * 5 + i] = 1.f / (1.f + expf(-(pv + bp2[0])));
    }
}

extern "C" void kernel_launch(void* const* d_in, const int* in_sizes, int n_in,
                              void* d_out, int out_size, void* d_ws, size_t ws_size,
                              hipStream_t stream) {
    const float* node_feats = (const float*)d_in[0];
    const int*   edge_index = (const int*)d_in[1];
    const float* edge_feats = (const float*)d_in[2];
    const float* W_in = (const float*)d_in[3];
    const float* b_in = (const float*)d_in[4];
    const float* W_m1 = (const float*)d_in[5];
    const float* b_m1 = (const float*)d_in[6];
    const float* W_m2 = (const float*)d_in[7];
    const float* b_m2 = (const float*)d_in[8];
    const float* W_z  = (const float*)d_in[9];
    const float* b_z  = (const float*)d_in[10];
    const float* W_r  = (const float*)d_in[11];
    const float* b_r  = (const float*)d_in[12];
    const float* W_h  = (const float*)d_in[13];
    const float* b_h  = (const float*)d_in[14];
    const float* ln_s = (const float*)d_in[15];
    const float* ln_b = (const float*)d_in[16];
    const float* W_c1 = (const float*)d_in[17];
    const float* b_c1 = (const float*)d_in[18];
    const float* W_c2 = (const float*)d_in[19];
    const float* b_c2 = (const float*)d_in[20];
    const float* W_p1 = (const float*)d_in[21];
    const float* b_p1 = (const float*)d_in[22];
    const float* W_p2 = (const float*)d_in[23];
    const float* b_p2 = (const float*)d_in[24];

    const int N = in_sizes[0] / 8;
    const int E = in_sizes[2] / 4;

    char* ws = (char*)d_ws;
    size_t off = 0;
    auto alloc = [&](size_t bytes) { size_t p = off; off = (off + bytes + 255) & ~(size_t)255; return p; };
    const size_t o_hf = alloc((size_t)N * 128 * 4);   // f32 h
    const size_t o_X  = alloc((size_t)N * 256 * 4);   // f32 [agg|Xd->T]
    const size_t o_pk = alloc((size_t)STEPS * 294912 * 2);
    const size_t o_deg = alloc((size_t)N * 4);
    const size_t o_off = alloc((size_t)(N + 1) * 4);
    const size_t o_cur = alloc((size_t)N * 4);
    const size_t o_ex  = alloc((size_t)N * 4);
    const size_t o_bs  = alloc(1024 * 4);
    const size_t o_be  = alloc(1024 * 4);
    const size_t o_ss  = alloc((size_t)E * 4);
    const size_t o_ei  = alloc((size_t)E * 4);

    if (off > ws_size) {  // fail cleanly (diagnosable) instead of faulting
        hipMemsetAsync(d_out, 0, (size_t)out_size * 4, stream);
        return;
    }

    float* hf = (float*)(ws + o_hf);
    float* X  = (float*)(ws + o_X);

    // ---- CSR by dst ----
    hipMemsetAsync(ws + o_deg, 0, (size_t)N * 4, stream);
    hipMemsetAsync(ws + o_cur, 0, (size_t)N * 4, stream);
    hist_k<<<(E + 255) / 256, 256, 0, stream>>>(edge_index + E, (int*)(ws + o_deg), E);
    const int nb1 = (N + 1023) / 1024;
    scan1_k<<<nb1, 256, 0, stream>>>((int*)(ws + o_deg), (int*)(ws + o_ex), (int*)(ws + o_bs), N);
    scan2_k<<<1, 1024, 0, stream>>>((int*)(ws + o_bs), (int*)(ws + o_be), nb1);
    scan3_k<<<(N + 1 + 255) / 256, 256, 0, stream>>>((int*)(ws + o_ex), (int*)(ws + o_be),
                                                     (int*)(ws + o_off), N, E);
    scatter_k<<<(E + 255) / 256, 256, 0, stream>>>(edge_index, edge_index + E, (int*)(ws + o_off),
                                                   (int*)(ws + o_cur), (int*)(ws + o_ss),
                                                   (int*)(ws + o_ei), E);
    // ---- pack weights (hi+lo planes) ----
    pack_k<<<dim3(16, STEPS, 5), 256, 0, stream>>>(W_m1, W_m2, W_z, W_r, W_h,
                                                   (unsigned short*)(ws + o_pk));
    // ---- input projection (f32) ----
    proj_k<<<(N + 3) / 4, 256, 0, stream>>>(node_feats, W_in, b_in, hf, N);

    const int MB = (N + 127) / 128;

    for (int s = 0; s < STEPS; ++s) {
        const unsigned short* pk = (const unsigned short*)(ws + o_pk) + (size_t)s * 294912;
        const unsigned short* pkL = pk + 147456;
        // X = [h@W1_src | h@W1_dst]  (f32)
        gemm_k<0><<<dim3(MB, 2), 256, 0, stream>>>(hf, 128, pk, pkL, nullptr, nullptr,
                                                   X, 256, N);
        // T[v] = sum relu(Xs + Xd + ef@Wef + b1) -> X[:,128:256]
        edge_k<<<(N + 3) / 4, 256, 0, stream>>>(X, (int*)(ws + o_off), (int*)(ws + o_ss),
                                                (int*)(ws + o_ei), (const float4*)edge_feats,
                                                W_m1 + (size_t)s * 33280, b_m1 + (size_t)s * 128, N);
        // agg = T@W2 + deg*b_m2 -> X[:,0:128]
        gemm_k<1><<<dim3(MB, 1), 256, 0, stream>>>(X + 128, 256, pk + 32768, pkL + 32768,
                                                   b_m2 + (size_t)s * 128, (int*)(ws + o_deg),
                                                   X, 256, N);
        // fused gates + candidate + blend + LN (in-place hf; rh via LDS)
        zrh_k<<<MB, 256, 0, stream>>>(hf, X,
                                      pk + 49152, pkL + 49152,     // Wz hi/lo
                                      pk + 81920, pkL + 81920,     // Wr hi/lo
                                      pk + 114688, pkL + 114688,   // Wh hi/lo
                                      b_z + (size_t)s * 128, b_r + (size_t)s * 128,
                                      b_h + (size_t)s * 128,
                                      ln_s + (size_t)s * 128, ln_b + (size_t)s * 128, N);
    }

    head_k<<<(N + 3) / 4, 256, 0, stream>>>(hf, W_c1, b_c1, W_c2, b_c2, W_p1, b_p1, W_p2, b_p2,
                                            (float*)d_out, N);
}

// Round 9
// 3331.620 us; speedup vs baseline: 1.2699x; 1.1530x over previous
//
#include <hip/hip_runtime.h>

#define STEPS 6

typedef __attribute__((ext_vector_type(8))) short short8;
typedef __attribute__((ext_vector_type(4))) float f32x4;
typedef __attribute__((ext_vector_type(8))) float f32x8;

__device__ __forceinline__ float bf2f(unsigned int u16) {
    union { unsigned int u; float f; } v; v.u = u16 << 16; return v.f;
}
__device__ __forceinline__ unsigned int f2bf(float x) {
    union { float f; unsigned int u; } v; v.f = x;
    unsigned int r = v.u + 0x7fffu + ((v.u >> 16) & 1u);
    return r >> 16;
}
__device__ __forceinline__ void decompv(const f32x8& v, short8& hi, short8& lo) {
#pragma unroll
    for (int j = 0; j < 8; ++j) {
        float x = v[j];
        unsigned int h = f2bf(x);
        hi[j] = (short)h;
        lo[j] = (short)f2bf(x - bf2f(h));
    }
}
// async global->LDS, 16B per lane: LDS dst = uniform base + lane*16
__device__ __forceinline__ void gl_lds16(const void* g, void* s) {
    __builtin_amdgcn_global_load_lds(
        (const __attribute__((address_space(1))) unsigned int*)g,
        (__attribute__((address_space(3))) unsigned int*)s, 16, 0, 0);
}

// ---------------- CSR build ----------------
__global__ __launch_bounds__(256) void hist_k(const int* __restrict__ dst, int* __restrict__ deg, int E) {
    int e = blockIdx.x * 256 + threadIdx.x;
    if (e < E) atomicAdd(&deg[dst[e]], 1);
}

__global__ __launch_bounds__(256) void scan1_k(const int* __restrict__ in, int* __restrict__ ex,
                                               int* __restrict__ bs, int N) {
    __shared__ int sd[256];
    int t = threadIdx.x;
    int base = blockIdx.x * 1024 + t * 4;
    int v[4]; int s = 0;
#pragma unroll
    for (int i = 0; i < 4; ++i) { int idx = base + i; v[i] = idx < N ? in[idx] : 0; s += v[i]; }
    sd[t] = s; __syncthreads();
    for (int o = 1; o < 256; o <<= 1) {
        int x = (t >= o) ? sd[t - o] : 0;
        __syncthreads();
        sd[t] += x;
        __syncthreads();
    }
    int run = sd[t] - s;
#pragma unroll
    for (int i = 0; i < 4; ++i) { int idx = base + i; if (idx < N) ex[idx] = run; run += v[i]; }
    if (t == 255) bs[blockIdx.x] = sd[255];
}

__global__ __launch_bounds__(1024) void scan2_k(const int* __restrict__ bs, int* __restrict__ be, int nb) {
    __shared__ int sd[1024];
    int t = threadIdx.x;
    int v = (t < nb) ? bs[t] : 0;
    sd[t] = v; __syncthreads();
    for (int o = 1; o < 1024; o <<= 1) {
        int x = (t >= o) ? sd[t - o] : 0;
        __syncthreads();
        sd[t] += x;
        __syncthreads();
    }
    if (t < nb) be[t] = sd[t] - v;
}

__global__ __launch_bounds__(256) void scan3_k(const int* __restrict__ ex, const int* __restrict__ be,
                                               int* __restrict__ offs, int N, int E) {
    int i = blockIdx.x * 256 + threadIdx.x;
    if (i < N) offs[i] = ex[i] + be[i >> 10];
    if (i == N) offs[N] = E;
}

__global__ __launch_bounds__(256) void scatter_k(const int* __restrict__ src, const int* __restrict__ dst,
                                                 const int* __restrict__ offs,
                                                 int* __restrict__ cursor, int* __restrict__ src_sorted,
                                                 int* __restrict__ eid_sorted, int E) {
    int e = blockIdx.x * 256 + threadIdx.x;
    if (e >= E) return;
    int d = dst[e];
    int pos = offs[d] + atomicAdd(&cursor[d], 1);
    src_sorted[pos] = src[e];
    eid_sorted[pos] = e;
}

// ---------------- weight packing: hi+lo bf16 planes, B-fragment order ----------------
// frag addr: ((ct*KS + ks)*64 + lane)*8 + j ; k = ks*32 + (lane>>4)*8 + j, col = ct*16 + (lane&15)
// per-step (stride 294912 elems): hi plane at +0, lo plane at +147456
// mat offsets (elems): W1:0 (32768), W2:32768 (16384), Wz:49152, Wr:81920, Wh:114688
__global__ __launch_bounds__(256) void pack_k(const float* __restrict__ W_m1, const float* __restrict__ W_m2,
                                              const float* __restrict__ W_z, const float* __restrict__ W_r,
                                              const float* __restrict__ W_h, unsigned short* __restrict__ packed) {
    const int s = blockIdx.y, mat = blockIdx.z;
    const int t = blockIdx.x * 256 + threadIdx.x;
    const int lane = t & 63;
    int KS, width; size_t moff;
    if (mat == 0)      { KS = 4; width = 256; moff = 0; }
    else if (mat == 1) { KS = 4; width = 128; moff = 32768; }
    else if (mat == 2) { KS = 8; width = 128; moff = 49152; }
    else if (mat == 3) { KS = 8; width = 128; moff = 81920; }
    else               { KS = 8; width = 128; moff = 114688; }
    const int total = (width >> 4) * KS * 64;
    if (t >= total) return;
    const int ks = (t >> 6) % KS;
    const int ct = (t >> 6) / KS;
    const int col = ct * 16 + (lane & 15);
    const int kb = ks * 32 + (lane >> 4) * 8;
    unsigned short* dh = packed + (size_t)s * 294912 + moff;
    unsigned short* dl = dh + 147456;
#pragma unroll
    for (int j = 0; j < 8; ++j) {
        const int k = kb + j;
        float v;
        if (mat == 0) {
            const float* W = W_m1 + (size_t)s * 260 * 128;
            v = (col < 128) ? W[k * 128 + col] : W[(128 + k) * 128 + (col - 128)];
        } else if (mat == 1) {
            v = W_m2[(size_t)s * 16384 + k * 128 + col];
        } else if (mat == 2) {
            v = W_z[(size_t)s * 32768 + k * 128 + col];
        } else if (mat == 3) {
            v = W_r[(size_t)s * 32768 + k * 128 + col];
        } else {
            v = W_h[(size_t)s * 32768 + k * 128 + col];
        }
        unsigned int hb = f2bf(v);
        dh[(size_t)t * 8 + j] = (unsigned short)hb;
        dl[(size_t)t * 8 + j] = (unsigned short)f2bf(v - bf2f(hb));
    }
}

// ---------------- input projection -> f32 h ----------------
__global__ __launch_bounds__(256) void proj_k(const float* __restrict__ nf, const float* __restrict__ Win,
                                              const float* __restrict__ bin,
                                              float* __restrict__ hf, int N) {
    const int lane = threadIdx.x & 63, wave = threadIdx.x >> 6;
    const int i = blockIdx.x * 4 + wave;
    if (i >= N) return;
    const int c0 = lane * 2;
    float a0 = bin[c0], a1 = bin[c0 + 1];
#pragma unroll
    for (int q = 0; q < 8; ++q) {
        float x = nf[(size_t)i * 8 + q];
        a0 += x * Win[q * 128 + c0];
        a1 += x * Win[q * 128 + c0 + 1];
    }
    hf[(size_t)i * 128 + c0] = a0;
    hf[(size_t)i * 128 + c0 + 1] = a1;
}

// ---------------- f32-accurate MFMA GEMM, LDS-staged weights (K=128) ----------------
// MODE 0: X = h@[W1s|W1d] : A=hf lda=128, out=X ldo=256 (cols cgrp*128..)
// MODE 1: agg = T@W2 + deg*b : A=X+128 lda=256, out=X ldo=256 (cols 0:128)
template <int MODE>
__global__ __launch_bounds__(256, 3) void gemm_k(const float* __restrict__ A, int lda,
                                                 const unsigned short* __restrict__ pkh,
                                                 const unsigned short* __restrict__ pkl,
                                                 const float* __restrict__ bias,
                                                 const int* __restrict__ deg,
                                                 float* __restrict__ out, int ldo,
                                                 int Nrows) {
    __shared__ char stg[2][16384];  // 16 lines x 1KB, double-buffered
    const int lane = threadIdx.x & 63;
    const int wave = threadIdx.x >> 6;
    const int l15 = lane & 15, l16 = lane >> 4;
    const int mbase = blockIdx.x * 128 + wave * 32;
    const int cgrp = blockIdx.y;

    int r0 = mbase + l15;      if (r0 >= Nrows) r0 = 0;
    int r1 = mbase + 16 + l15; if (r1 >= Nrows) r1 = 0;
    const float* a0p = A + (size_t)r0 * lda;
    const float* a1p = A + (size_t)r1 * lda;

    f32x4 acc[2][8];
#pragma unroll
    for (int rt = 0; rt < 2; ++rt)
#pragma unroll
        for (int ct = 0; ct < 8; ++ct) acc[rt][ct] = (f32x4){0.f, 0.f, 0.f, 0.f};

    auto STG = [&](int buf, int ks) {
#pragma unroll
        for (int i = 0; i < 4; ++i) {
            const int line = wave * 4 + i;
            const int ct = line & 7;
            const unsigned short* src = (line & 8) ? pkl : pkh;
            gl_lds16((const char*)src + (((size_t)(cgrp * 8 + ct) * 4 + ks) << 10) + lane * 16,
                     &stg[buf][line << 10]);
        }
    };

    STG(0, 0);
    __syncthreads();
    int buf = 0;
    for (int ks = 0; ks < 4; ++ks) {
        if (ks < 3) STG(buf ^ 1, ks + 1);
        const int k = ks * 32 + l16 * 8;
        short8 ahi[2], alo[2];
        decompv(*(const f32x8*)(a0p + k), ahi[0], alo[0]);
        decompv(*(const f32x8*)(a1p + k), ahi[1], alo[1]);
        const char* sb = stg[buf];
#pragma unroll
        for (int ct = 0; ct < 8; ++ct) {
            const short8 wh = *(const short8*)(sb + (ct << 10) + lane * 16);
            const short8 wl = *(const short8*)(sb + ((8 + ct) << 10) + lane * 16);
#pragma unroll
            for (int rt = 0; rt < 2; ++rt) {
                acc[rt][ct] = __builtin_amdgcn_mfma_f32_16x16x32_bf16(ahi[rt], wh, acc[rt][ct], 0, 0, 0);
                acc[rt][ct] = __builtin_amdgcn_mfma_f32_16x16x32_bf16(alo[rt], wh, acc[rt][ct], 0, 0, 0);
                acc[rt][ct] = __builtin_amdgcn_mfma_f32_16x16x32_bf16(ahi[rt], wl, acc[rt][ct], 0, 0, 0);
            }
        }
        __syncthreads();
        buf ^= 1;
    }
#pragma unroll
    for (int rt = 0; rt < 2; ++rt) {
#pragma unroll
        for (int ct = 0; ct < 8; ++ct) {
            const int col = cgrp * 128 + ct * 16 + l15;
#pragma unroll
            for (int r = 0; r < 4; ++r) {
                const int row = mbase + rt * 16 + l16 * 4 + r;
                if (row >= Nrows) continue;
                float v = acc[rt][ct][r];
                if (MODE == 1) v += bias[col] * (float)deg[row];
                out[(size_t)row * ldo + col] = v;
            }
        }
    }
}

// ---------------- fused z,r,rh,hn,blend,LN — 64 rows/block, 16 rows/wave ----------------
// phase1 (K=256, single-buffer stage + counted vmcnt): z, r over [h|agg]; hn_bot = agg@Wh_bot (ks>=4)
// phase2: z=sig; rh=sig(r)*h -> LDS (stride-132 rows, 2-way max aliasing)
// phase3 (K=128): hn += rh@Wh_top, Wh_top direct from L2
// phase4: blend + LN -> hf
__global__ __launch_bounds__(256, 3) void zrh_k(float* __restrict__ hf,
                                                const float* __restrict__ X,  // [N,256]: 0:128 agg
                                                const unsigned short* __restrict__ pzh, const unsigned short* __restrict__ pzl,
                                                const unsigned short* __restrict__ prh, const unsigned short* __restrict__ prl,
                                                const unsigned short* __restrict__ phh, const unsigned short* __restrict__ phl,
                                                const float* __restrict__ bz, const float* __restrict__ br,
                                                const float* __restrict__ bh,
                                                const float* __restrict__ lns, const float* __restrict__ lnb,
                                                int N) {
    __shared__ char stg[49152];   // phase1: up to 48 weight lines x 1KB; phase2/3: rh f32 [4][16][132]
    float* rhs = reinterpret_cast<float*>(stg);
    const int lane = threadIdx.x & 63;
    const int wave = threadIdx.x >> 6;
    const int l15 = lane & 15, l16 = lane >> 4;
    const int mrow = blockIdx.x * 64 + wave * 16;

    int r0 = mrow + l15; if (r0 >= N) r0 = 0;

    f32x4 zac[8], rac[8], hac[8];
#pragma unroll
    for (int ct = 0; ct < 8; ++ct) {
        zac[ct] = (f32x4){0.f, 0.f, 0.f, 0.f};
        rac[ct] = (f32x4){0.f, 0.f, 0.f, 0.f};
        hac[ct] = (f32x4){0.f, 0.f, 0.f, 0.f};
    }

    // stage lines: plane*8+ct ; planes 0=zh 1=zl 2=rh 3=rl (+ ks>=4: 4=hbh 5=hbl)
    auto STGzr = [&](int ks) {
#pragma unroll
        for (int i = 0; i < 8; ++i) {
            const int line = wave + 4 * i;          // 0..31
            const int plane = line >> 3, ct = line & 7;
            const unsigned short* src = (plane == 0) ? pzh : (plane == 1) ? pzl
                                       : (plane == 2) ? prh : prl;
            gl_lds16((const char*)src + (((size_t)(ct * 8 + ks)) << 10) + lane * 16,
                     &stg[line << 10]);
        }
    };
    auto STGhb = [&](int ks) {
#pragma unroll
        for (int i = 0; i < 4; ++i) {
            const int line = 32 + wave + 4 * i;     // 32..47
            const int plane = (line - 32) >> 3, ct = line & 7;
            const unsigned short* src = plane ? phl : phh;
            gl_lds16((const char*)src + (((size_t)(ct * 8 + ks)) << 10) + lane * 16,
                     &stg[line << 10]);
        }
    };

    // ---- phase 1 ----
    f32x8 acur = *(const f32x8*)(hf + (size_t)r0 * 128 + l16 * 8);
    for (int ks = 0; ks < 8; ++ks) {
        STGzr(ks);
        if (ks >= 4) STGhb(ks);
        f32x8 anext;
        if (ks < 7) {
            const int kn = (ks + 1) * 32 + l16 * 8;
            const float* ap = (kn < 128) ? (hf + (size_t)r0 * 128 + kn)
                                         : (X + (size_t)r0 * 256 + (kn - 128));
            float4 pa = *(const float4*)ap;
            float4 pb = *(const float4*)(ap + 4);
            anext[0] = pa.x; anext[1] = pa.y; anext[2] = pa.z; anext[3] = pa.w;
            anext[4] = pb.x; anext[5] = pb.y; anext[6] = pb.z; anext[7] = pb.w;
        }
        short8 ahi, alo;
        decompv(acur, ahi, alo);
        if (ks < 7) asm volatile("s_waitcnt vmcnt(2)" ::: "memory");
        else        asm volatile("s_waitcnt vmcnt(0)" ::: "memory");
        __builtin_amdgcn_sched_barrier(0);
        __builtin_amdgcn_s_barrier();
        __builtin_amdgcn_sched_barrier(0);
#pragma unroll
        for (int ct = 0; ct < 8; ++ct) {
            const short8 wzh = *(const short8*)(stg + ((0 * 8 + ct) << 10) + lane * 16);
            const short8 wzl = *(const short8*)(stg + ((1 * 8 + ct) << 10) + lane * 16);
            const short8 wrh = *(const short8*)(stg + ((2 * 8 + ct) << 10) + lane * 16);
            const short8 wrl = *(const short8*)(stg + ((3 * 8 + ct) << 10) + lane * 16);
            zac[ct] = __builtin_amdgcn_mfma_f32_16x16x32_bf16(ahi, wzh, zac[ct], 0, 0, 0);
            zac[ct] = __builtin_amdgcn_mfma_f32_16x16x32_bf16(alo, wzh, zac[ct], 0, 0, 0);
            zac[ct] = __builtin_amdgcn_mfma_f32_16x16x32_bf16(ahi, wzl, zac[ct], 0, 0, 0);
            rac[ct] = __builtin_amdgcn_mfma_f32_16x16x32_bf16(ahi, wrh, rac[ct], 0, 0, 0);
            rac[ct] = __builtin_amdgcn_mfma_f32_16x16x32_bf16(alo, wrh, rac[ct], 0, 0, 0);
            rac[ct] = __builtin_amdgcn_mfma_f32_16x16x32_bf16(ahi, wrl, rac[ct], 0, 0, 0);
            if (ks >= 4) {
                const short8 wbh = *(const short8*)(stg + ((4 * 8 + ct) << 10) + lane * 16);
                const short8 wbl = *(const short8*)(stg + ((5 * 8 + ct) << 10) + lane * 16);
                hac[ct] = __builtin_amdgcn_mfma_f32_16x16x32_bf16(ahi, wbh, hac[ct], 0, 0, 0);
                hac[ct] = __builtin_amdgcn_mfma_f32_16x16x32_bf16(alo, wbh, hac[ct], 0, 0, 0);
                hac[ct] = __builtin_amdgcn_mfma_f32_16x16x32_bf16(ahi, wbl, hac[ct], 0, 0, 0);
            }
        }
        __builtin_amdgcn_sched_barrier(0);
        __builtin_amdgcn_s_barrier();
        acur = anext;
    }

    // ---- phase 2: z = sigmoid (keep); rh = sigmoid(r)*h -> LDS [wave][row][132] ----
#pragma unroll
    for (int ct = 0; ct < 8; ++ct) {
        const int col = ct * 16 + l15;
#pragma unroll
        for (int r = 0; r < 4; ++r) {
            const int rowl = l16 * 4 + r;
            const int row = mrow + rowl;
            const size_t idx = (size_t)(row < N ? row : 0) * 128 + col;
            float zp = zac[ct][r] + bz[col];
            zac[ct][r] = 1.f / (1.f + expf(-zp));
            float rp = rac[ct][r] + br[col];
            float rr = 1.f / (1.f + expf(-rp));
            rhs[wave * 2112 + rowl * 132 + col] = rr * hf[idx];
        }
    }
    __syncthreads();

    // ---- phase 3: hn += rh @ Wh_top (K=128), Wh_top direct from global (L2-hot) ----
    for (int ks = 0; ks < 4; ++ks) {
        const f32x8 v = *(const f32x8*)(rhs + wave * 2112 + l15 * 132 + (ks * 4 + l16) * 8);
        short8 ahi, alo;
        decompv(v, ahi, alo);
#pragma unroll
        for (int ct = 0; ct < 8; ++ct) {
            const size_t fb = ((size_t)(ct * 8 + ks) << 10) + lane * 16;
            const short8 wh = *(const short8*)((const char*)phh + fb);
            const short8 wl = *(const short8*)((const char*)phl + fb);
            hac[ct] = __builtin_amdgcn_mfma_f32_16x16x32_bf16(ahi, wh, hac[ct], 0, 0, 0);
            hac[ct] = __builtin_amdgcn_mfma_f32_16x16x32_bf16(alo, wh, hac[ct], 0, 0, 0);
            hac[ct] = __builtin_amdgcn_mfma_f32_16x16x32_bf16(ahi, wl, hac[ct], 0, 0, 0);
        }
    }

    // ---- phase 4: blend + LayerNorm -> hf ----
#pragma unroll
    for (int ct = 0; ct < 8; ++ct) {
        const int col = ct * 16 + l15;
#pragma unroll
        for (int r = 0; r < 4; ++r) {
            const int row = mrow + l16 * 4 + r;
            const size_t idx = (size_t)(row < N ? row : 0) * 128 + col;
            float hn = tanhf(hac[ct][r] + bh[col]);
            float zz = zac[ct][r];
            hac[ct][r] = (1.f - zz) * hf[idx] + zz * hn;
        }
    }
#pragma unroll
    for (int r = 0; r < 4; ++r) {
        const int row = mrow + l16 * 4 + r;
        float s = 0.f, ss = 0.f;
#pragma unroll
        for (int ct = 0; ct < 8; ++ct) {
            float y = hac[ct][r];
            s += y; ss += y * y;
        }
#pragma unroll
        for (int m = 1; m < 16; m <<= 1) {
            s += __shfl_xor(s, m, 64);
            ss += __shfl_xor(ss, m, 64);
        }
        float mean = s * (1.f / 128.f);
        float var = ss * (1.f / 128.f) - mean * mean;
        float inv = rsqrtf(var + 1e-6f);
        if (row < N) {
#pragma unroll
            for (int ct = 0; ct < 8; ++ct) {
                const int col = ct * 16 + l15;
                hf[(size_t)row * 128 + col] = (hac[ct][r] - mean) * inv * lns[col] + lnb[col];
            }
        }
    }
}

// ---------------- edge accumulate (f32): T[v] = sum relu(Xs[src]+Xd[v]+ef@Wef+b1) -> X[:,128:256] ----
__global__ __launch_bounds__(256) void edge_k(float* __restrict__ X,
                                              const int* __restrict__ offs,
                                              const int* __restrict__ src_sorted,
                                              const int* __restrict__ eid_sorted,
                                              const float4* __restrict__ ef_all,
                                              const float* __restrict__ Wm1_s,
                                              const float* __restrict__ bm1_s,
                                              int N) {
    const int lane = threadIdx.x & 63, wave = threadIdx.x >> 6;
    const int v = blockIdx.x * 4 + wave;
    if (v >= N) return;
    const int c0 = lane * 2;
    const float base0 = X[(size_t)v * 256 + 128 + c0] + bm1_s[c0];
    const float base1 = X[(size_t)v * 256 + 129 + c0] + bm1_s[c0 + 1];
    const float w0x = Wm1_s[256 * 128 + c0], w0y = Wm1_s[256 * 128 + c0 + 1];
    const float w1x = Wm1_s[257 * 128 + c0], w1y = Wm1_s[257 * 128 + c0 + 1];
    const float w2x = Wm1_s[258 * 128 + c0], w2y = Wm1_s[258 * 128 + c0 + 1];
    const float w3x = Wm1_s[259 * 128 + c0], w3y = Wm1_s[259 * 128 + c0 + 1];
    float acc0 = 0.f, acc1 = 0.f;
    const int beg = offs[v], end = offs[v + 1];
    for (int i = beg; i < end; ++i) {
        int sn = src_sorted[i];
        int eid = eid_sorted[i];
        float4 ef = ef_all[eid];
        float2 xs = *reinterpret_cast<const float2*>(X + (size_t)sn * 256 + c0);
        float e0 = ef.x * w0x + ef.y * w1x + ef.z * w2x + ef.w * w3x;
        float e1 = ef.x * w0y + ef.y * w1y + ef.z * w2y + ef.w * w3y;
        acc0 += fmaxf(xs.x + base0 + e0, 0.f);
        acc1 += fmaxf(xs.y + base1 + e1, 0.f);
    }
    X[(size_t)v * 256 + 128 + c0] = acc0;   // T overwrites Xd (consumed above)
    X[(size_t)v * 256 + 129 + c0] = acc1;
}

// ---------------- heads (f32) ----------------
__global__ __launch_bounds__(256) void head_k(const float* __restrict__ h,
                                              const float* __restrict__ Wc1, const float* __restrict__ bc1,
                                              const float* __restrict__ Wc2, const float* __restrict__ bc2,
                                              const float* __restrict__ Wp1, const float* __restrict__ bp1,
                                              const float* __restrict__ Wp2, const float* __restrict__ bp2,
                                              float* __restrict__ out, int N) {
    __shared__ float sh[4][128];
    const int lane = threadIdx.x & 63, wave = threadIdx.x >> 6;
    const int i = blockIdx.x * 4 + wave;
    if (i >= N) return;
    float2 hv = *reinterpret_cast<const float2*>(h + (size_t)i * 128 + lane * 2);
    sh[wave][lane * 2] = hv.x; sh[wave][lane * 2 + 1] = hv.y;
    float t1 = bc1[lane], t2 = bp1[lane];
    for (int k = 0; k < 128; ++k) {
        float hk = sh[wave][k];
        t1 += hk * Wc1[k * 64 + lane];
        t2 += hk * Wp1[k * 64 + lane];
    }
    t1 = fmaxf(t1, 0.f); t2 = fmaxf(t2, 0.f);
    float c[5];
#pragma unroll
    for (int cc = 0; cc < 5; ++cc) {
        float vv = t1 * Wc2[lane * 5 + cc];
        for (int o = 1; o < 64; o <<= 1) vv += __shfl_xor(vv, o, 64);
        c[cc] = vv;
    }
    float pv = t2 * Wp2[lane];
    for (int o = 1; o < 64; o <<= 1) pv += __shfl_xor(pv, o, 64);
    if (lane == 0) {
#pragma unroll
        for (int cc = 0; cc < 5; ++cc) out[(size_t)i * 5 + cc] = c[cc] + bc2[cc];
        out[(size_t)N * 5 + i] = 1.f / (1.f + expf(-(pv + bp2[0])));
    }
}

extern "C" void kernel_launch(void* const* d_in, const int* in_sizes, int n_in,
                              void* d_out, int out_size, void* d_ws, size_t ws_size,
                              hipStream_t stream) {
    const float* node_feats = (const float*)d_in[0];
    const int*   edge_index = (const int*)d_in[1];
    const float* edge_feats = (const float*)d_in[2];
    const float* W_in = (const float*)d_in[3];
    const float* b_in = (const float*)d_in[4];
    const float* W_m1 = (const float*)d_in[5];
    const float* b_m1 = (const float*)d_in[6];
    const float* W_m2 = (const float*)d_in[7];
    const float* b_m2 = (const float*)d_in[8];
    const float* W_z  = (const float*)d_in[9];
    const float* b_z  = (const float*)d_in[10];
    const float* W_r  = (const float*)d_in[11];
    const float* b_r  = (const float*)d_in[12];
    const float* W_h  = (const float*)d_in[13];
    const float* b_h  = (const float*)d_in[14];
    const float* ln_s = (const float*)d_in[15];
    const float* ln_b = (const float*)d_in[16];
    const float* W_c1 = (const float*)d_in[17];
    const float* b_c1 = (const float*)d_in[18];
    const float* W_c2 = (const float*)d_in[19];
    const float* b_c2 = (const float*)d_in[20];
    const float* W_p1 = (const float*)d_in[21];
    const float* b_p1 = (const float*)d_in[22];
    const float* W_p2 = (const float*)d_in[23];
    const float* b_p2 = (const float*)d_in[24];

    const int N = in_sizes[0] / 8;
    const int E = in_sizes[2] / 4;

    char* ws = (char*)d_ws;
    size_t off = 0;
    auto alloc = [&](size_t bytes) { size_t p = off; off = (off + bytes + 255) & ~(size_t)255; return p; };
    const size_t o_hf = alloc((size_t)N * 128 * 4);   // f32 h
    const size_t o_X  = alloc((size_t)N * 256 * 4);   // f32 [agg|Xd->T]
    const size_t o_pk = alloc((size_t)STEPS * 294912 * 2);
    const size_t o_deg = alloc((size_t)N * 4);
    const size_t o_off = alloc((size_t)(N + 1) * 4);
    const size_t o_cur = alloc((size_t)N * 4);
    const size_t o_ex  = alloc((size_t)N * 4);
    const size_t o_bs  = alloc(1024 * 4);
    const size_t o_be  = alloc(1024 * 4);
    const size_t o_ss  = alloc((size_t)E * 4);
    const size_t o_ei  = alloc((size_t)E * 4);

    if (off > ws_size) {  // fail cleanly (diagnosable) instead of faulting
        hipMemsetAsync(d_out, 0, (size_t)out_size * 4, stream);
        return;
    }

    float* hf = (float*)(ws + o_hf);
    float* X  = (float*)(ws + o_X);

    // ---- CSR by dst ----
    hipMemsetAsync(ws + o_deg, 0, (size_t)N * 4, stream);
    hipMemsetAsync(ws + o_cur, 0, (size_t)N * 4, stream);
    hist_k<<<(E + 255) / 256, 256, 0, stream>>>(edge_index + E, (int*)(ws + o_deg), E);
    const int nb1 = (N + 1023) / 1024;
    scan1_k<<<nb1, 256, 0, stream>>>((int*)(ws + o_deg), (int*)(ws + o_ex), (int*)(ws + o_bs), N);
    scan2_k<<<1, 1024, 0, stream>>>((int*)(ws + o_bs), (int*)(ws + o_be), nb1);
    scan3_k<<<(N + 1 + 255) / 256, 256, 0, stream>>>((int*)(ws + o_ex), (int*)(ws + o_be),
                                                     (int*)(ws + o_off), N, E);
    scatter_k<<<(E + 255) / 256, 256, 0, stream>>>(edge_index, edge_index + E, (int*)(ws + o_off),
                                                   (int*)(ws + o_cur), (int*)(ws + o_ss),
                                                   (int*)(ws + o_ei), E);
    // ---- pack weights (hi+lo planes) ----
    pack_k<<<dim3(16, STEPS, 5), 256, 0, stream>>>(W_m1, W_m2, W_z, W_r, W_h,
                                                   (unsigned short*)(ws + o_pk));
    // ---- input projection (f32) ----
    proj_k<<<(N + 3) / 4, 256, 0, stream>>>(node_feats, W_in, b_in, hf, N);

    const int MB = (N + 127) / 128;
    const int MB2 = (N + 63) / 64;

    for (int s = 0; s < STEPS; ++s) {
        const unsigned short* pk = (const unsigned short*)(ws + o_pk) + (size_t)s * 294912;
        const unsigned short* pkL = pk + 147456;
        // X = [h@W1_src | h@W1_dst]  (f32)
        gemm_k<0><<<dim3(MB, 2), 256, 0, stream>>>(hf, 128, pk, pkL, nullptr, nullptr,
                                                   X, 256, N);
        // T[v] = sum relu(Xs + Xd + ef@Wef + b1) -> X[:,128:256]
        edge_k<<<(N + 3) / 4, 256, 0, stream>>>(X, (int*)(ws + o_off), (int*)(ws + o_ss),
                                                (int*)(ws + o_ei), (const float4*)edge_feats,
                                                W_m1 + (size_t)s * 33280, b_m1 + (size_t)s * 128, N);
        // agg = T@W2 + deg*b_m2 -> X[:,0:128]
        gemm_k<1><<<dim3(MB, 1), 256, 0, stream>>>(X + 128, 256, pk + 32768, pkL + 32768,
                                                   b_m2 + (size_t)s * 128, (int*)(ws + o_deg),
                                                   X, 256, N);
        // fused gates + candidate + blend + LN (in-place hf; rh via LDS)
        zrh_k<<<MB2, 256, 0, stream>>>(hf, X,
                                       pk + 49152, pkL + 49152,     // Wz hi/lo
                                       pk + 81920, pkL + 81920,     // Wr hi/lo
                                       pk + 114688, pkL + 114688,   // Wh hi/lo
                                       b_z + (size_t)s * 128, b_r + (size_t)s * 128,
                                       b_h + (size_t)s * 128,
                                       ln_s + (size_t)s * 128, ln_b + (size_t)s * 128, N);
    }

    head_k<<<(N + 3) / 4, 256, 0, stream>>>(hf, W_c1, b_c1, W_c2, b_c2, W_p1, b_p1, W_p2, b_p2,
                                            (float*)d_out, N);
}